// Round 5
// baseline (364.651 us; speedup 1.0000x reference)
//
#include <hip/hip_runtime.h>
#include <hip/hip_bf16.h>
#include <cstddef>

#define NN 100000
#define NE 1600000
#define NG 2000
#define NS 40
#define INF 64
#define F 128
#define FFN_DIM 1024
#define NB 782            // ceil(100000/128) buckets of 128 nodes
#define BCAP 3072         // fixed bucket capacity (mean 2048, sigma 45 -> 19+ sigma margin)
#define SC_BLOCKS 512
#define SC_CHUNK 3125     // 512*3125 = 1.6M edges exactly
#define KSPLIT 8

using bf16 = __hip_bfloat16;
using bf162 = __hip_bfloat162;
typedef __attribute__((ext_vector_type(8))) short short8;
typedef __attribute__((ext_vector_type(4))) float f32x4;
typedef __attribute__((ext_vector_type(2))) float f32x2;

__device__ __forceinline__ short f2bs(float f){
    union { bf16 b; short s; } u; u.b = __float2bfloat16(f); return u.s;
}

// ---------------- init bucket cursors to fixed region starts ----------------
__global__ __launch_bounds__(1024) void k_binit(int* __restrict__ bcursor){
    int t = threadIdx.x;
    if (t < NB) bcursor[t] = t * BCAP;
}

// ---------------- xws = (x @ W_gcn) * dinv[row], bf16 MFMA, stored fp8 e4m3 ----------------
// Computes C^T: A-operand = W features (M dim), B-operand = x rows (N dim).
// D layout (m89): N index = lane&15 -> x-row; M index = quad*4+reg -> 4 CONSECUTIVE
// features per lane -> direct cvt_pk_fp8 packing into one dword store.
__global__ __launch_bounds__(256) void k_xws(const float* __restrict__ x, const float* __restrict__ W,
                                             const float* __restrict__ dinv, unsigned char* __restrict__ xws8){
    __shared__ short Xs[128*72];   // [row][k], stride 72
    __shared__ short Ws[128*72];   // [feature][k], stride 72
    int t = threadIdx.x;
    int rowBase = blockIdx.x * 128;
    // stage W [64][128] fp32 -> Ws[n][k] bf16
    #pragma unroll
    for (int i=0;i<32;i++){
        int id = i*256+t; int k = id>>7, n = id&127;
        Ws[n*72 + k] = f2bs(W[id]);
    }
    // stage x rows [128][64] fp32 -> Xs[r][k] bf16 (packed dword writes)
    #pragma unroll
    for (int i=0;i<8;i++){
        int id = i*256+t;              // 2048 float4 slots
        int r = id>>4; int k4 = (id&15)*4;
        int row = rowBase + r; if (row >= NN) row = NN-1;
        float4 v = *(const float4*)&x[(size_t)row*INF + k4];
        unsigned int u0 = (unsigned int)(unsigned short)f2bs(v.x) | ((unsigned int)(unsigned short)f2bs(v.y)<<16);
        unsigned int u1 = (unsigned int)(unsigned short)f2bs(v.z) | ((unsigned int)(unsigned short)f2bs(v.w)<<16);
        *(unsigned int*)&Xs[r*72 + k4]     = u0;
        *(unsigned int*)&Xs[r*72 + k4 + 2] = u1;
    }
    __syncthreads();
    int lane = t & 63, w = t >> 6;
    int lr = lane & 15, quad = lane >> 4;
    f32x4 acc[2][8];
    #pragma unroll
    for (int i=0;i<2;i++)
        #pragma unroll
        for (int j=0;j<8;j++) acc[i][j] = (f32x4){0.f,0.f,0.f,0.f};
    #pragma unroll
    for (int ks=0; ks<2; ++ks){
        int kb = ks*32 + quad*8;
        short8 b0 = *(const short8*)&Xs[((w  )*16 + lr)*72 + kb];
        short8 b1 = *(const short8*)&Xs[((w+4)*16 + lr)*72 + kb];
        #pragma unroll
        for (int mt=0; mt<8; ++mt){
            short8 a = *(const short8*)&Ws[(mt*16 + lr)*72 + kb];
            acc[0][mt] = __builtin_amdgcn_mfma_f32_16x16x32_bf16(a, b0, acc[0][mt], 0, 0, 0);
            acc[1][mt] = __builtin_amdgcn_mfma_f32_16x16x32_bf16(a, b1, acc[1][mt], 0, 0, 0);
        }
    }
    #pragma unroll
    for (int rt=0; rt<2; ++rt){
        int row = rowBase + (w + rt*4)*16 + lr;
        if (row < NN){
            float dv = dinv[row];
            #pragma unroll
            for (int mt=0; mt<8; ++mt){
                int p = __builtin_amdgcn_cvt_pk_fp8_f32(acc[rt][mt][0]*dv, acc[rt][mt][1]*dv, 0, false);
                p     = __builtin_amdgcn_cvt_pk_fp8_f32(acc[rt][mt][2]*dv, acc[rt][mt][3]*dv, p, true);
                *(int*)&xws8[(size_t)row*F + mt*16 + quad*4] = p;
            }
        }
    }
}

// ---------------- binned scatter: pack (row<<7|col&127) into fixed bucket regions ----------------
__global__ __launch_bounds__(1024) void k_scatter2(const int* __restrict__ ei, int* __restrict__ bcursor,
                                                   int* __restrict__ ebuf){
    __shared__ int lh[NB];
    __shared__ int lb[NB];
    int t = threadIdx.x;
    int base = blockIdx.x * SC_CHUNK;
    for (int b=t; b<NB; b+=1024) lh[b] = 0;
    __syncthreads();
    int rr[4], cc[4];
    #pragma unroll
    for (int q=0;q<4;q++){
        int i = t + q*1024;
        bool v = (i < SC_CHUNK);
        int idx = v ? (base + i) : base;
        rr[q] = ei[idx];
        cc[q] = ei[NE + idx];
        if (v) atomicAdd(&lh[cc[q]>>7], 1);
    }
    __syncthreads();
    for (int b=t; b<NB; b+=1024){
        int n = lh[b];
        lb[b] = n ? atomicAdd(&bcursor[b], n) : 0;
        lh[b] = 0;
    }
    __syncthreads();
    #pragma unroll
    for (int q=0;q<4;q++){
        int i = t + q*1024;
        if (i < SC_CHUNK){
            int b = cc[q] >> 7;
            int rk = atomicAdd(&lh[b], 1);
            ebuf[lb[b] + rk] = (rr[q] << 7) | (cc[q] & 127);
        }
    }
}

// ---------------- per-bucket counting sort; emits PRE-MULTIPLIED word offsets ----------------
// Bucket size derived from bcursor (fixed regions), no bstart scan needed.
__global__ __launch_bounds__(256) void k_sort(const int* __restrict__ ebuf, const int* __restrict__ bcursor,
                                              int* __restrict__ cnt, float* __restrict__ dinv,
                                              int* __restrict__ nstart, int* __restrict__ ebuf2){
    __shared__ int lh[128];
    __shared__ int s[128];
    __shared__ int lcur[128];
    int t = threadIdx.x;
    int b = blockIdx.x;
    int e0 = b * BCAP;
    int nE = bcursor[b] - e0;
    if (t < 128) lh[t] = 0;
    __syncthreads();
    for (int i=t; i<nE; i+=256) atomicAdd(&lh[ebuf[e0+i] & 127], 1);
    __syncthreads();
    int c = (t < 128) ? lh[t] : 0;
    if (t < 128) s[t] = c;
    __syncthreads();
    #pragma unroll
    for (int off=1; off<128; off<<=1){
        int v = (t >= off && t < 128) ? s[t-off] : 0;
        __syncthreads();
        if (t < 128) s[t] += v;
        __syncthreads();
    }
    int node = b*128 + t;
    if (t < 128){
        int excl = s[t] - c;
        lcur[t] = excl;
        if (node < NN){
            nstart[node] = e0 + excl;
            cnt[node] = c;
            dinv[node] = rsqrtf((float)c + 2.0f);
        }
    }
    __syncthreads();
    for (int i=t; i<nE; i+=256){
        int v = ebuf[e0 + i];
        int nl = v & 127;
        int rk = atomicAdd(&lcur[nl], 1);
        ebuf2[e0 + rk] = (v >> 7) << 5;   // row * 32 (uint-word offset into xws8)
    }
}

// ---------------- fused: CSR gather + GCN epilogue + BN + ReLU -> h,hb + pool + pre-LN ----------------
// One block per graph. 16 lane-groups of 16 lanes; each group owns its own node
// (slot sid = w*4 + (lane>>4); nodes i = sid, sid+16, sid+32, ...).
// Gather: 16 lanes x dwordx2 = 128B row per edge -> 4 edges per load instr per wave;
// unroll 8 -> 32 gathers in flight per wave. No cross-lane combine (lane owns 8 features).
__global__ __launch_bounds__(256) void k_aggpool(const unsigned char* __restrict__ xws8,
                                                 const int* __restrict__ nstart, const int* __restrict__ cnt,
                                                 const float* __restrict__ dinv, const float* __restrict__ b_gcn,
                                                 const float* __restrict__ bn_g, const float* __restrict__ bn_b,
                                                 const int* __restrict__ ebuf2,
                                                 const float* __restrict__ lnpre_g, const float* __restrict__ lnpre_b,
                                                 float* __restrict__ h, unsigned short* __restrict__ hb,
                                                 float* __restrict__ z, float* __restrict__ zn){
    __shared__ float zacc[16][128];
    int t = threadIdx.x;
    int lane = t & 63, w = t >> 6;
    int gl = lane & 15;                 // lane within group
    int sid = w*4 + (lane >> 4);        // node slot 0..15
    int g = blockIdx.x;
    const unsigned int* xw32 = (const unsigned int*)xws8;   // row stride = 32 uints

    float4 bg_lo  = *(const float4*)&b_gcn[8*gl];
    float4 bg_hi  = *(const float4*)&b_gcn[8*gl+4];
    float4 bng_lo = *(const float4*)&bn_g[8*gl];
    float4 bng_hi = *(const float4*)&bn_g[8*gl+4];
    float4 bnb_lo = *(const float4*)&bn_b[8*gl];
    float4 bnb_hi = *(const float4*)&bn_b[8*gl+4];
    const float bns = rsqrtf(1.f + 1e-5f);

    float za[8];
    #pragma unroll
    for (int k=0;k<8;k++) za[k] = 0.f;

    for (int i = sid; i < 50; i += 16){
        int node = g*50 + i;
        int s0n = nstart[node]; int dg = cnt[node]; float dv = dinv[node];
        uint2 us = *(const uint2*)&xw32[node*32 + gl*2];   // self-loop, issued early
        float acc[8];
        #pragma unroll
        for (int k=0;k<8;k++) acc[k] = 0.f;
        int j=0;
        for (; j+8<=dg; j+=8){
            int r[8];
            #pragma unroll
            for (int q=0;q<8;q++) r[q] = ebuf2[s0n+j+q];
            uint2 u[8];
            #pragma unroll
            for (int q=0;q<8;q++) u[q] = *(const uint2*)&xw32[r[q] + gl*2];
            #pragma unroll
            for (int q=0;q<8;q++){
                f32x2 f0 = __builtin_amdgcn_cvt_pk_f32_fp8(u[q].x, false);
                f32x2 f1 = __builtin_amdgcn_cvt_pk_f32_fp8(u[q].x, true);
                f32x2 f2 = __builtin_amdgcn_cvt_pk_f32_fp8(u[q].y, false);
                f32x2 f3 = __builtin_amdgcn_cvt_pk_f32_fp8(u[q].y, true);
                acc[0] += f0.x; acc[1] += f0.y; acc[2] += f1.x; acc[3] += f1.y;
                acc[4] += f2.x; acc[5] += f2.y; acc[6] += f3.x; acc[7] += f3.y;
            }
        }
        for (; j<dg; ++j){
            int r0 = ebuf2[s0n+j];
            uint2 u0 = *(const uint2*)&xw32[r0 + gl*2];
            f32x2 f0 = __builtin_amdgcn_cvt_pk_f32_fp8(u0.x, false);
            f32x2 f1 = __builtin_amdgcn_cvt_pk_f32_fp8(u0.x, true);
            f32x2 f2 = __builtin_amdgcn_cvt_pk_f32_fp8(u0.y, false);
            f32x2 f3 = __builtin_amdgcn_cvt_pk_f32_fp8(u0.y, true);
            acc[0] += f0.x; acc[1] += f0.y; acc[2] += f1.x; acc[3] += f1.y;
            acc[4] += f2.x; acc[5] += f2.y; acc[6] += f3.x; acc[7] += f3.y;
        }
        // self-loop + bias + BN + ReLU (features 8*gl .. 8*gl+7)
        f32x2 s0 = __builtin_amdgcn_cvt_pk_f32_fp8(us.x, false);
        f32x2 s1 = __builtin_amdgcn_cvt_pk_f32_fp8(us.x, true);
        f32x2 s2 = __builtin_amdgcn_cvt_pk_f32_fp8(us.y, false);
        f32x2 s3 = __builtin_amdgcn_cvt_pk_f32_fp8(us.y, true);
        float p[8];
        p[0] = dv*(acc[0] + 2.f*s0.x) + bg_lo.x;
        p[1] = dv*(acc[1] + 2.f*s0.y) + bg_lo.y;
        p[2] = dv*(acc[2] + 2.f*s1.x) + bg_lo.z;
        p[3] = dv*(acc[3] + 2.f*s1.y) + bg_lo.w;
        p[4] = dv*(acc[4] + 2.f*s2.x) + bg_hi.x;
        p[5] = dv*(acc[5] + 2.f*s2.y) + bg_hi.y;
        p[6] = dv*(acc[6] + 2.f*s3.x) + bg_hi.z;
        p[7] = dv*(acc[7] + 2.f*s3.y) + bg_hi.w;
        p[0] = fmaxf(p[0]*bns*bng_lo.x + bnb_lo.x, 0.f);
        p[1] = fmaxf(p[1]*bns*bng_lo.y + bnb_lo.y, 0.f);
        p[2] = fmaxf(p[2]*bns*bng_lo.z + bnb_lo.z, 0.f);
        p[3] = fmaxf(p[3]*bns*bng_lo.w + bnb_lo.w, 0.f);
        p[4] = fmaxf(p[4]*bns*bng_hi.x + bnb_hi.x, 0.f);
        p[5] = fmaxf(p[5]*bns*bng_hi.y + bnb_hi.y, 0.f);
        p[6] = fmaxf(p[6]*bns*bng_hi.z + bnb_hi.z, 0.f);
        p[7] = fmaxf(p[7]*bns*bng_hi.w + bnb_hi.w, 0.f);
        // stores: h fp32 (2x float4), hb bf16 (uint4) — 16 lanes contiguous
        *(float4*)&h[(size_t)node*F + 8*gl]     = make_float4(p[0],p[1],p[2],p[3]);
        *(float4*)&h[(size_t)node*F + 8*gl + 4] = make_float4(p[4],p[5],p[6],p[7]);
        uint4 hb4;
        hb4.x = (unsigned int)(unsigned short)f2bs(p[0]) | ((unsigned int)(unsigned short)f2bs(p[1])<<16);
        hb4.y = (unsigned int)(unsigned short)f2bs(p[2]) | ((unsigned int)(unsigned short)f2bs(p[3])<<16);
        hb4.z = (unsigned int)(unsigned short)f2bs(p[4]) | ((unsigned int)(unsigned short)f2bs(p[5])<<16);
        hb4.w = (unsigned int)(unsigned short)f2bs(p[6]) | ((unsigned int)(unsigned short)f2bs(p[7])<<16);
        *(uint4*)&hb[(size_t)node*F + 8*gl] = hb4;
        #pragma unroll
        for (int k=0;k<8;k++) za[k] += p[k];
    }
    // pool: slot partials -> LDS
    *(float4*)&zacc[sid][8*gl]     = make_float4(za[0],za[1],za[2],za[3]);
    *(float4*)&zacc[sid][8*gl + 4] = make_float4(za[4],za[5],za[6],za[7]);
    __syncthreads();
    if (w == 0){
        int lh = lane & 31, half = lane >> 5;
        float s0=0.f, s1=0.f, s2=0.f, s3=0.f;
        #pragma unroll
        for (int sd=0; sd<16; ++sd){
            float4 v = *(const float4*)&zacc[sd][4*lh];
            s0 += v.x; s1 += v.y; s2 += v.z; s3 += v.w;
        }
        s0 /= 50.0f; s1 /= 50.0f; s2 /= 50.0f; s3 /= 50.0f;
        if (half == 0)
            *(float4*)&z[(size_t)g*F + 4*lh] = make_float4(s0,s1,s2,s3);
        float s = (s0+s1)+(s2+s3);
        #pragma unroll
        for (int off=1; off<32; off<<=1) s += __shfl_xor(s, off);
        float m = s * (1.f/128.f);
        float d0=s0-m, d1=s1-m, d2=s2-m, d3=s3-m;
        float vv = (d0*d0+d1*d1)+(d2*d2+d3*d3);
        #pragma unroll
        for (int off=1; off<32; off<<=1) vv += __shfl_xor(vv, off);
        float rs = rsqrtf(vv*(1.f/128.f) + 1e-5f);
        float4 lg = *(const float4*)&lnpre_g[4*lh];
        float4 lb = *(const float4*)&lnpre_b[4*lh];
        if (half == 0)
            *(float4*)&zn[(size_t)g*F + 4*lh] = make_float4(d0*rs*lg.x+lb.x, d1*rs*lg.y+lb.y,
                                                            d2*rs*lg.z+lb.z, d3*rs*lg.w+lb.w);
    }
}

// ---------------- fused: ap = ao@Wo + bo; zd1 = LN(z + ap) ----------------
// 32 rows x 128 cols per block (full rows -> in-block LN via half-wave shfl).
__global__ __launch_bounds__(256) void k_wo_ln(const float* __restrict__ ao, const float* __restrict__ Wo,
                                               const float* __restrict__ bo, const float* __restrict__ z,
                                               const float* __restrict__ g, const float* __restrict__ b,
                                               float* __restrict__ zd1){
    __shared__ float As[32*36];
    __shared__ float Bs[32*128];
    int t = threadIdx.x;
    int rowBase = blockIdx.x*32;
    int c0 = (t&31)*4, r0 = (t>>5)*4;
    float acc[4][4];
    #pragma unroll
    for (int i=0;i<4;i++){ acc[i][0]=0.f; acc[i][1]=0.f; acc[i][2]=0.f; acc[i][3]=0.f; }
    for (int kb=0; kb<F; kb+=32){
        #pragma unroll
        for (int i=0;i<4;i++){
            int id = i*256+t; int kk = id&31; int r = id>>5;
            int row = rowBase + r;
            As[kk*36+r] = (row<NG) ? ao[(size_t)row*F + kb + kk] : 0.f;
        }
        #pragma unroll
        for (int i=0;i<16;i++){
            int id = i*256+t; int c = id&127; int kk = id>>7;
            Bs[kk*128+c] = Wo[(size_t)(kb+kk)*F + c];
        }
        __syncthreads();
        for (int kk=0;kk<32;kk++){
            float4 a = *(const float4*)&As[kk*36+r0];
            float4 bv = *(const float4*)&Bs[kk*128+c0];
            float av[4]={a.x,a.y,a.z,a.w}; float bb[4]={bv.x,bv.y,bv.z,bv.w};
            #pragma unroll
            for(int i=0;i<4;i++)
                #pragma unroll
                for(int j=0;j<4;j++) acc[i][j] += av[i]*bb[j];
        }
        __syncthreads();
    }
    float4 bo4 = *(const float4*)&bo[c0];
    float4 g4  = *(const float4*)&g[c0];
    float4 b4  = *(const float4*)&b[c0];
    #pragma unroll
    for (int i=0;i<4;i++){
        int row = rowBase + r0 + i;
        float v0=0.f,v1=0.f,v2=0.f,v3=0.f;
        if (row < NG){
            float4 zr = *(const float4*)&z[(size_t)row*F + c0];
            v0 = acc[i][0] + bo4.x + zr.x;
            v1 = acc[i][1] + bo4.y + zr.y;
            v2 = acc[i][2] + bo4.z + zr.z;
            v3 = acc[i][3] + bo4.w + zr.w;
        }
        float s = (v0+v1)+(v2+v3);
        #pragma unroll
        for (int off=1; off<32; off<<=1) s += __shfl_xor(s, off);
        float m = s * (1.f/128.f);
        float d0=v0-m, d1=v1-m, d2=v2-m, d3=v3-m;
        float vv = (d0*d0+d1*d1)+(d2*d2+d3*d3);
        #pragma unroll
        for (int off=1; off<32; off<<=1) vv += __shfl_xor(vv, off);
        float rs = rsqrtf(vv*(1.f/128.f) + 1e-5f);
        if (row < NG)
            *(float4*)&zd1[(size_t)row*F + c0] = make_float4(d0*rs*g4.x+b4.x, d1*rs*g4.y+b4.y,
                                                             d2*rs*g4.z+b4.z, d3*rs*g4.w+b4.w);
    }
}

// ---------------- fused: zd2 = LN(zd1 + sum(part) + b2); gsi = zd2 @ Wg_bot + bg ----------------
__global__ __launch_bounds__(256) void k_ln_red_gsi(const float* __restrict__ A, const float* __restrict__ part,
                                                    const float* __restrict__ bias, const float* __restrict__ g,
                                                    const float* __restrict__ b, const float* __restrict__ Wb,
                                                    const float* __restrict__ bg, float* __restrict__ zd2,
                                                    float* __restrict__ gsi){
    __shared__ float Zs[4][128];
    __shared__ float Bs[32*128];
    int t = threadIdx.x; int lane = t&63;
    int rquad = t>>6;
    int row = blockIdx.x*4 + rquad;
    int i0 = row*F + 2*lane;
    float x0 = A[i0] + bias[2*lane], x1 = A[i0+1] + bias[2*lane+1];
    #pragma unroll
    for (int zz=0; zz<KSPLIT; ++zz){
        x0 += part[(size_t)zz*NG*F + i0];
        x1 += part[(size_t)zz*NG*F + i0 + 1];
    }
    float s = x0+x1;
    for (int off=1; off<64; off<<=1) s += __shfl_xor(s, off);
    float m = s * (1.f/128.f);
    float d0 = x0-m, d1 = x1-m;
    float vv = d0*d0 + d1*d1;
    for (int off=1; off<64; off<<=1) vv += __shfl_xor(vv, off);
    float rs = rsqrtf(vv*(1.f/128.f) + 1e-5f);
    float o0 = d0*rs*g[2*lane]   + b[2*lane];
    float o1 = d1*rs*g[2*lane+1] + b[2*lane+1];
    zd2[i0]   = o0;
    zd2[i0+1] = o1;
    Zs[rquad][2*lane]   = o0;
    Zs[rquad][2*lane+1] = o1;
    __syncthreads();
    // gsi phase: thread t handles col (t&127) for rows rp and rp+2
    int col = t & 127, rp = t >> 7;
    float a0=0.f, a1=0.f;
    for (int kb=0; kb<F; kb+=32){
        #pragma unroll
        for (int i=0;i<16;i++){
            int id = i*256+t; int c = id&127; int kk = id>>7;
            Bs[kk*128+c] = Wb[(size_t)(kb+kk)*F + c];
        }
        __syncthreads();
        for (int kk=0;kk<32;kk++){
            float w = Bs[kk*128+col];
            a0 += Zs[rp][kb+kk]   * w;
            a1 += Zs[rp+2][kb+kk] * w;
        }
        __syncthreads();
    }
    float bgc = bg[col];
    gsi[(size_t)(blockIdx.x*4 + rp)*F + col]     = a0 + bgc;
    gsi[(size_t)(blockIdx.x*4 + rp + 2)*F + col] = a1 + bgc;
}

// ---------------- generic small GEMM: C = A[MxK] @ B[KxN] + bias, opt ReLU ----------------
template<int RELU>
__global__ __launch_bounds__(256) void k_gemm(const float* __restrict__ A, const float* __restrict__ B,
                                              const float* __restrict__ bias, float* __restrict__ C,
                                              int M, int K, int Nc){
    __shared__ float As[32*68];
    __shared__ float Bs[32*64];
    int t = threadIdx.x;
    int rowBase = blockIdx.x*64;
    int colBase = blockIdx.y*64;
    int c0 = (t&15)*4, r0 = (t>>4)*4;
    float acc[4][4];
    #pragma unroll
    for (int i=0;i<4;i++){ acc[i][0]=0.f; acc[i][1]=0.f; acc[i][2]=0.f; acc[i][3]=0.f; }
    for (int kb=0; kb<K; kb+=32){
        #pragma unroll
        for (int i=0;i<8;i++){
            int id = i*256+t; int kk = id&31; int r = id>>5;
            int row = rowBase + r;
            As[kk*68+r] = (row<M) ? A[(size_t)row*K + kb + kk] : 0.f;
        }
        #pragma unroll
        for (int i=0;i<8;i++){
            int id = i*256+t; int c = id&63; int kk = id>>6;
            Bs[kk*64+c] = B[(size_t)(kb+kk)*Nc + colBase + c];
        }
        __syncthreads();
        for (int kk=0;kk<32;kk++){
            float4 a = *(const float4*)&As[kk*68+r0];
            float4 b = *(const float4*)&Bs[kk*64+c0];
            float av[4]={a.x,a.y,a.z,a.w}; float bv[4]={b.x,b.y,b.z,b.w};
            #pragma unroll
            for(int i=0;i<4;i++)
                #pragma unroll
                for(int j=0;j<4;j++) acc[i][j] += av[i]*bv[j];
        }
        __syncthreads();
    }
    for (int i=0;i<4;i++){
        int row = rowBase + r0 + i;
        if (row < M){
            for (int j=0;j<4;j++){
                float v = acc[i][j] + bias[colBase+c0+j];
                if (RELU) v = fmaxf(v, 0.f);
                C[(size_t)row*Nc + colBase + c0 + j] = v;
            }
        }
    }
}

// ---------------- split-K GEMM: part[z] = A[:, zK:(z+1)K] @ B[zK:(z+1)K, :] (no bias) ----------------
__global__ __launch_bounds__(256) void k_gemm_splitk(const float* __restrict__ A, const float* __restrict__ B,
                                                     float* __restrict__ part, int M, int K, int Nc){
    __shared__ float As[32*68];
    __shared__ float Bs[32*64];
    int t = threadIdx.x;
    int rowBase = blockIdx.x*64;
    int colBase = blockIdx.y*64;
    int z = blockIdx.z;
    int kchunk = K / KSPLIT;
    int kbeg = z * kchunk;
    int c0 = (t&15)*4, r0 = (t>>4)*4;
    float acc[4][4];
    #pragma unroll
    for (int i=0;i<4;i++){ acc[i][0]=0.f; acc[i][1]=0.f; acc[i][2]=0.f; acc[i][3]=0.f; }
    for (int kb=kbeg; kb<kbeg+kchunk; kb+=32){
        #pragma unroll
        for (int i=0;i<8;i++){
            int id = i*256+t; int kk = id&31; int r = id>>5;
            int row = rowBase + r;
            As[kk*68+r] = (row<M) ? A[(size_t)row*K + kb + kk] : 0.f;
        }
        #pragma unroll
        for (int i=0;i<8;i++){
            int id = i*256+t; int c = id&63; int kk = id>>6;
            Bs[kk*64+c] = B[(size_t)(kb+kk)*Nc + colBase + c];
        }
        __syncthreads();
        for (int kk=0;kk<32;kk++){
            float4 a = *(const float4*)&As[kk*68+r0];
            float4 b = *(const float4*)&Bs[kk*64+c0];
            float av[4]={a.x,a.y,a.z,a.w}; float bv[4]={b.x,b.y,b.z,b.w};
            #pragma unroll
            for(int i=0;i<4;i++)
                #pragma unroll
                for(int j=0;j<4;j++) acc[i][j] += av[i]*bv[j];
        }
        __syncthreads();
    }
    float* Cp = part + (size_t)z*M*Nc;
    for (int i=0;i<4;i++){
        int row = rowBase + r0 + i;
        if (row < M){
            for (int j=0;j<4;j++)
                Cp[(size_t)row*Nc + colBase + c0 + j] = acc[i][j];
        }
    }
}

// ---------------- fused QKV projections (A shared; blockIdx.z selects weights) ----------------
__global__ __launch_bounds__(256) void k_gemm_qkv(const float* __restrict__ A,
                                                  const float* __restrict__ Wq, const float* __restrict__ Wk,
                                                  const float* __restrict__ Wv, const float* __restrict__ bq,
                                                  const float* __restrict__ bk, const float* __restrict__ bv,
                                                  float* __restrict__ Cq, float* __restrict__ Ck,
                                                  float* __restrict__ Cv){
    __shared__ float As[32*68];
    __shared__ float Bs[32*64];
    int t = threadIdx.x;
    int rowBase = blockIdx.x*64;
    int colBase = blockIdx.y*64;
    int z = blockIdx.z;
    const float* B = (z==0) ? Wq : (z==1) ? Wk : Wv;
    const float* bias = (z==0) ? bq : (z==1) ? bk : bv;
    float* C = (z==0) ? Cq : (z==1) ? Ck : Cv;
    int c0 = (t&15)*4, r0 = (t>>4)*4;
    float acc[4][4];
    #pragma unroll
    for (int i=0;i<4;i++){ acc[i][0]=0.f; acc[i][1]=0.f; acc[i][2]=0.f; acc[i][3]=0.f; }
    for (int kb=0; kb<F; kb+=32){
        #pragma unroll
        for (int i=0;i<8;i++){
            int id = i*256+t; int kk = id&31; int r = id>>5;
            int row = rowBase + r;
            As[kk*68+r] = (row<NG) ? A[(size_t)row*F + kb + kk] : 0.f;
        }
        #pragma unroll
        for (int i=0;i<8;i++){
            int id = i*256+t; int c = id&63; int kk = id>>6;
            Bs[kk*64+c] = B[(size_t)(kb+kk)*F + colBase + c];
        }
        __syncthreads();
        for (int kk=0;kk<32;kk++){
            float4 a = *(const float4*)&As[kk*68+r0];
            float4 b = *(const float4*)&Bs[kk*64+c0];
            float av[4]={a.x,a.y,a.z,a.w}; float bv4[4]={b.x,b.y,b.z,b.w};
            #pragma unroll
            for(int i=0;i<4;i++)
                #pragma unroll
                for(int j=0;j<4;j++) acc[i][j] += av[i]*bv4[j];
        }
        __syncthreads();
    }
    for (int i=0;i<4;i++){
        int row = rowBase + r0 + i;
        if (row < NG){
            for (int j=0;j<4;j++)
                C[(size_t)row*F + colBase + c0 + j] = acc[i][j] + bias[colBase+c0+j];
        }
    }
}

// ---------------- attention: one block per (set, head) ----------------
__global__ __launch_bounds__(256) void k_attn(const float* __restrict__ q, const float* __restrict__ k,
                                              const float* __restrict__ v, float* __restrict__ o){
    __shared__ float Qs[1600], Ks[1600], Vs[1600], Sc[2500];
    int t = threadIdx.x;
    int s = blockIdx.x >> 2; int hh = blockIdx.x & 3;
    for (int idx=t; idx<1600; idx+=256){
        int i = idx>>5, d = idx&31;
        size_t gi = (size_t)(s*50+i)*F + hh*32 + d;
        Qs[idx]=q[gi]; Ks[idx]=k[gi]; Vs[idx]=v[gi];
    }
    __syncthreads();
    for (int idx=t; idx<2500; idx+=256){
        int qi = idx/50, ki = idx%50;
        float acc=0.f;
        #pragma unroll 8
        for (int d=0;d<32;d++) acc += Qs[qi*32+d]*Ks[ki*32+d];
        Sc[idx] = acc * 0.17677669529663687f;   // 1/sqrt(32)
    }
    __syncthreads();
    if (t < 50){
        float m=-1e30f;
        for (int j=0;j<50;j++) m = fmaxf(m, Sc[t*50+j]);
        float sum=0.f;
        for (int j=0;j<50;j++){ float e=__expf(Sc[t*50+j]-m); Sc[t*50+j]=e; sum+=e; }
        float inv = 1.f/sum;
        for (int j=0;j<50;j++) Sc[t*50+j] *= inv;
    }
    __syncthreads();
    for (int idx=t; idx<1600; idx+=256){
        int qi = idx>>5, d = idx&31;
        float acc=0.f;
        #pragma unroll 10
        for (int ki=0;ki<50;ki++) acc += Sc[qi*50+ki]*Vs[ki*32+d];
        o[(size_t)(s*50+qi)*F + hh*32 + d] = acc;
    }
}

// ---------------- MFMA gate: L = h @ Wg_top (bf16 MFMA), out = sig(L+gsi)*zd2 + (1-sig)*h ----------------
__global__ __launch_bounds__(256) void k_gate_mfma(const float* __restrict__ h,
                                                   const unsigned short* __restrict__ hb,
                                                   const float* __restrict__ Wg,
                                                   const float* __restrict__ gsi, const float* __restrict__ zd2,
                                                   float* __restrict__ out){
    __shared__ short Bw[128*136];   // Wg_top^T as bf16, [n][k], stride 136 (2-way bank alias = free)
    int t = threadIdx.x;
    for (int i=t; i<16384; i+=256){
        int k = i >> 7, n = i & 127;
        Bw[n*136 + k] = f2bs(Wg[(size_t)k*F + n]);
    }
    __syncthreads();
    int lane = t & 63, w = t >> 6;
    int lr = lane & 15, quad = lane >> 4;
    int mrow0 = blockIdx.x*128 + w*32;
    f32x4 acc[2][8];
    #pragma unroll
    for (int i=0;i<2;i++)
        #pragma unroll
        for (int j=0;j<8;j++) acc[i][j] = (f32x4){0.f,0.f,0.f,0.f};
    #pragma unroll
    for (int ks=0; ks<4; ++ks){
        int kb = ks*32 + quad*8;
        short8 a[2];
        #pragma unroll
        for (int mt=0; mt<2; ++mt){
            int row = mrow0 + mt*16 + lr;
            if (row >= NN) row = NN-1;
            a[mt] = *(const short8*)&hb[(size_t)row*F + kb];
        }
        #pragma unroll
        for (int nt=0; nt<8; ++nt){
            short8 b = *(const short8*)&Bw[(nt*16 + lr)*136 + kb];
            acc[0][nt] = __builtin_amdgcn_mfma_f32_16x16x32_bf16(a[0], b, acc[0][nt], 0, 0, 0);
            acc[1][nt] = __builtin_amdgcn_mfma_f32_16x16x32_bf16(a[1], b, acc[1][nt], 0, 0, 0);
        }
    }
    // epilogue: C/D layout col=lane&15, row=quad*4+reg
    #pragma unroll
    for (int mt=0; mt<2; ++mt){
        #pragma unroll
        for (int r=0; r<4; ++r){
            int row = mrow0 + mt*16 + quad*4 + r;
            if (row >= NN) continue;
            int g = row / 50;
            const float* gs = &gsi[(size_t)g*F];
            const float* zs = &zd2[(size_t)g*F];
            const float* hr = &h[(size_t)row*F];
            float* orow = &out[(size_t)row*F];
            #pragma unroll
            for (int nt=0; nt<8; ++nt){
                int col = nt*16 + lr;
                float L = acc[mt][nt][r] + gs[col];
                float gate = 1.f/(1.f + __expf(-L));
                orow[col] = gate*zs[col] + (1.f-gate)*hr[col];
            }
        }
    }
}

extern "C" void kernel_launch(void* const* d_in, const int* in_sizes, int n_in,
                              void* d_out, int out_size, void* d_ws, size_t ws_size,
                              hipStream_t stream) {
    const float* x      = (const float*)d_in[0];
    const int*   ei     = (const int*)d_in[1];
    const float* W_gcn  = (const float*)d_in[4];
    const float* b_gcn  = (const float*)d_in[5];
    const float* bn_g   = (const float*)d_in[6];
    const float* bn_b   = (const float*)d_in[7];
    const float* lnpre_g= (const float*)d_in[8];
    const float* lnpre_b= (const float*)d_in[9];
    const float* Wq     = (const float*)d_in[10];
    const float* bq     = (const float*)d_in[11];
    const float* Wk     = (const float*)d_in[12];
    const float* bk     = (const float*)d_in[13];
    const float* Wv     = (const float*)d_in[14];
    const float* bv     = (const float*)d_in[15];
    const float* Wo     = (const float*)d_in[16];
    const float* bo     = (const float*)d_in[17];
    const float* ln1_g  = (const float*)d_in[18];
    const float* ln1_b  = (const float*)d_in[19];
    const float* W1     = (const float*)d_in[20];
    const float* b1     = (const float*)d_in[21];
    const float* W2     = (const float*)d_in[22];
    const float* b2     = (const float*)d_in[23];
    const float* ln2_g  = (const float*)d_in[24];
    const float* ln2_b  = (const float*)d_in[25];
    const float* Wg     = (const float*)d_in[26];
    const float* bg     = (const float*)d_in[27];
    float* out = (float*)d_out;
    char* ws = (char*)d_ws;

    // workspace layout
    size_t o = 0;
    unsigned char* xws8 = (unsigned char*)(ws + o); o += (size_t)NN*F; // 12.8 MB (fp8)
    float* h     = (float*)(ws + o); o += (size_t)NN*F*4;            // 51.2 MB
    unsigned short* hb = (unsigned short*)(ws + o); o += (size_t)NN*F*2; // 25.6 MB (bf16)
    int*   cnt   = (int*)(ws + o);   o += (size_t)NN*4;
    int*   nstart= (int*)(ws + o);   o += (size_t)NN*4;
    int*   ebuf  = (int*)(ws + o);   o += (size_t)NB*BCAP*4;         // 9.6 MB
    int*   ebuf2 = (int*)(ws + o);   o += (size_t)NB*BCAP*4;         // 9.6 MB
    float* dinv  = (float*)(ws + o); o += (size_t)NN*4;
    int*   bcursor=(int*)(ws + o);   o += 1024*4;
    float* z     = (float*)(ws + o); o += (size_t)NG*F*4;
    float* zn    = (float*)(ws + o); o += (size_t)NG*F*4;
    float* qb    = (float*)(ws + o); o += (size_t)NG*F*4;
    float* kb2   = (float*)(ws + o); o += (size_t)NG*F*4;
    float* vb    = (float*)(ws + o); o += (size_t)NG*F*4;
    float* ao    = (float*)(ws + o); o += (size_t)NG*F*4;
    float* zd1   = (float*)(ws + o); o += (size_t)NG*F*4;
    float* ffn1  = (float*)(ws + o); o += (size_t)NG*FFN_DIM*4;      // 8.2 MB
    float* part  = (float*)(ws + o); o += (size_t)KSPLIT*NG*F*4;     // 8.2 MB
    float* zd2   = (float*)(ws + o); o += (size_t)NG*F*4;
    float* gsi   = (float*)(ws + o); o += (size_t)NG*F*4;

    // ---- GCN phase ----
    k_binit<<<1, 1024, 0, stream>>>(bcursor);
    k_scatter2<<<SC_BLOCKS, 1024, 0, stream>>>(ei, bcursor, ebuf);
    k_sort<<<NB, 256, 0, stream>>>(ebuf, bcursor, cnt, dinv, nstart, ebuf2);
    k_xws<<<(NN+127)/128, 256, 0, stream>>>(x, W_gcn, dinv, xws8);
    k_aggpool<<<NG, 256, 0, stream>>>(xws8, nstart, cnt, dinv, b_gcn, bn_g, bn_b, ebuf2,
                                      lnpre_g, lnpre_b, h, hb, z, zn);

    // ---- set transformer (fp32, tiny) ----
    dim3 gqkv(32, 2, 3);
    k_gemm_qkv<<<gqkv, 256, 0, stream>>>(zn, Wq, Wk, Wv, bq, bk, bv, qb, kb2, vb);
    k_attn<<<NS*4, 256, 0, stream>>>(qb, kb2, vb, ao);
    k_wo_ln<<<(NG+31)/32, 256, 0, stream>>>(ao, Wo, bo, z, ln1_g, ln1_b, zd1);
    dim3 gffn1(32, 16);
    k_gemm<1><<<gffn1, 256, 0, stream>>>(zd1, W1, b1, ffn1, NG, F, FFN_DIM);
    dim3 gsk(32, 2, KSPLIT);
    k_gemm_splitk<<<gsk, 256, 0, stream>>>(ffn1, W2, part, NG, FFN_DIM, F);
    k_ln_red_gsi<<<NG/4, 256, 0, stream>>>(zd1, part, b2, ln2_g, ln2_b,
                                           Wg + (size_t)F*F, bg, zd2, gsi);

    // ---- gated fusion -> output ----
    k_gate_mfma<<<782, 256, 0, stream>>>(h, hb, Wg, gsi, zd2, out);
}

// Round 6
// 354.040 us; speedup vs baseline: 1.0300x; 1.0300x over previous
//
#include <hip/hip_runtime.h>
#include <hip/hip_bf16.h>
#include <cstddef>

#define NN 100000
#define NE 1600000
#define NG 2000
#define NS 40
#define INF 64
#define F 128
#define FFN_DIM 1024
#define NB 782            // ceil(100000/128) buckets of 128 nodes
#define BCAP 3072         // fixed bucket capacity (mean 2048, sigma 45 -> 19+ sigma margin)
#define SC_BLOCKS 512
#define SC_CHUNK 3125     // 512*3125 = 1.6M edges exactly
#define KSPLIT 8

using bf16 = __hip_bfloat16;
typedef __attribute__((ext_vector_type(8))) short short8;
typedef __attribute__((ext_vector_type(4))) float f32x4;
typedef __attribute__((ext_vector_type(2))) float f32x2;

__device__ __forceinline__ short f2bs(float f){
    union { bf16 b; short s; } u; u.b = __float2bfloat16(f); return u.s;
}
__device__ __forceinline__ unsigned int pk2(float a, float b){
    return (unsigned int)(unsigned short)f2bs(a) | ((unsigned int)(unsigned short)f2bs(b) << 16);
}

// ---------------- init bucket cursors to fixed region starts ----------------
__global__ __launch_bounds__(1024) void k_binit(int* __restrict__ bcursor){
    int t = threadIdx.x;
    if (t < NB) bcursor[t] = t * BCAP;
}

// ---------------- xws = (x @ W_gcn) * dinv[row], bf16 MFMA, stored fp8 e4m3 ----------------
__global__ __launch_bounds__(256) void k_xws(const float* __restrict__ x, const float* __restrict__ W,
                                             const float* __restrict__ dinv, unsigned char* __restrict__ xws8){
    __shared__ short Xs[128*72];   // [row][k], stride 72
    __shared__ short Ws[128*72];   // [feature][k], stride 72
    int t = threadIdx.x;
    int rowBase = blockIdx.x * 128;
    #pragma unroll
    for (int i=0;i<32;i++){
        int id = i*256+t; int k = id>>7, n = id&127;
        Ws[n*72 + k] = f2bs(W[id]);
    }
    #pragma unroll
    for (int i=0;i<8;i++){
        int id = i*256+t;              // 2048 float4 slots
        int r = id>>4; int k4 = (id&15)*4;
        int row = rowBase + r; if (row >= NN) row = NN-1;
        float4 v = *(const float4*)&x[(size_t)row*INF + k4];
        *(unsigned int*)&Xs[r*72 + k4]     = pk2(v.x, v.y);
        *(unsigned int*)&Xs[r*72 + k4 + 2] = pk2(v.z, v.w);
    }
    __syncthreads();
    int lane = t & 63, w = t >> 6;
    int lr = lane & 15, quad = lane >> 4;
    f32x4 acc[2][8];
    #pragma unroll
    for (int i=0;i<2;i++)
        #pragma unroll
        for (int j=0;j<8;j++) acc[i][j] = (f32x4){0.f,0.f,0.f,0.f};
    #pragma unroll
    for (int ks=0; ks<2; ++ks){
        int kb = ks*32 + quad*8;
        short8 b0 = *(const short8*)&Xs[((w  )*16 + lr)*72 + kb];
        short8 b1 = *(const short8*)&Xs[((w+4)*16 + lr)*72 + kb];
        #pragma unroll
        for (int mt=0; mt<8; ++mt){
            short8 a = *(const short8*)&Ws[(mt*16 + lr)*72 + kb];
            acc[0][mt] = __builtin_amdgcn_mfma_f32_16x16x32_bf16(a, b0, acc[0][mt], 0, 0, 0);
            acc[1][mt] = __builtin_amdgcn_mfma_f32_16x16x32_bf16(a, b1, acc[1][mt], 0, 0, 0);
        }
    }
    #pragma unroll
    for (int rt=0; rt<2; ++rt){
        int row = rowBase + (w + rt*4)*16 + lr;
        if (row < NN){
            float dv = dinv[row];
            #pragma unroll
            for (int mt=0; mt<8; ++mt){
                int p = __builtin_amdgcn_cvt_pk_fp8_f32(acc[rt][mt][0]*dv, acc[rt][mt][1]*dv, 0, false);
                p     = __builtin_amdgcn_cvt_pk_fp8_f32(acc[rt][mt][2]*dv, acc[rt][mt][3]*dv, p, true);
                *(int*)&xws8[(size_t)row*F + mt*16 + quad*4] = p;
            }
        }
    }
}

// ---------------- binned scatter: pack (row<<7|col&127) into fixed bucket regions ----------------
__global__ __launch_bounds__(1024) void k_scatter2(const int* __restrict__ ei, int* __restrict__ bcursor,
                                                   int* __restrict__ ebuf){
    __shared__ int lh[NB];
    __shared__ int lb[NB];
    int t = threadIdx.x;
    int base = blockIdx.x * SC_CHUNK;
    for (int b=t; b<NB; b+=1024) lh[b] = 0;
    __syncthreads();
    int rr[4], cc[4];
    #pragma unroll
    for (int q=0;q<4;q++){
        int i = t + q*1024;
        bool v = (i < SC_CHUNK);
        int idx = v ? (base + i) : base;
        rr[q] = ei[idx];
        cc[q] = ei[NE + idx];
        if (v) atomicAdd(&lh[cc[q]>>7], 1);
    }
    __syncthreads();
    for (int b=t; b<NB; b+=1024){
        int n = lh[b];
        lb[b] = n ? atomicAdd(&bcursor[b], n) : 0;
        lh[b] = 0;
    }
    __syncthreads();
    #pragma unroll
    for (int q=0;q<4;q++){
        int i = t + q*1024;
        if (i < SC_CHUNK){
            int b = cc[q] >> 7;
            int rk = atomicAdd(&lh[b], 1);
            ebuf[lb[b] + rk] = (rr[q] << 7) | (cc[q] & 127);
        }
    }
}

// ---------------- per-bucket counting sort; emits PRE-MULTIPLIED word offsets ----------------
__global__ __launch_bounds__(256) void k_sort(const int* __restrict__ ebuf, const int* __restrict__ bcursor,
                                              int* __restrict__ cnt, float* __restrict__ dinv,
                                              int* __restrict__ nstart, int* __restrict__ ebuf2){
    __shared__ int lh[128];
    __shared__ int s[128];
    __shared__ int lcur[128];
    int t = threadIdx.x;
    int b = blockIdx.x;
    int e0 = b * BCAP;
    int nE = bcursor[b] - e0;
    if (t < 128) lh[t] = 0;
    __syncthreads();
    for (int i=t; i<nE; i+=256) atomicAdd(&lh[ebuf[e0+i] & 127], 1);
    __syncthreads();
    int c = (t < 128) ? lh[t] : 0;
    if (t < 128) s[t] = c;
    __syncthreads();
    #pragma unroll
    for (int off=1; off<128; off<<=1){
        int v = (t >= off && t < 128) ? s[t-off] : 0;
        __syncthreads();
        if (t < 128) s[t] += v;
        __syncthreads();
    }
    int node = b*128 + t;
    if (t < 128){
        int excl = s[t] - c;
        lcur[t] = excl;
        if (node < NN){
            nstart[node] = e0 + excl;
            cnt[node] = c;
            dinv[node] = rsqrtf((float)c + 2.0f);
        }
    }
    __syncthreads();
    for (int i=t; i<nE; i+=256){
        int v = ebuf[e0 + i];
        int nl = v & 127;
        int rk = atomicAdd(&lcur[nl], 1);
        ebuf2[e0 + rk] = (v >> 7) << 5;   // row * 32 (uint-word offset into xws8)
    }
}

// ---------------- fused: CSR gather (2 edges/wave-load) + GCN epilogue + BN + ReLU
//                  -> h (fp32) + hb (bf16) + pool + pre-LN -> z, zn, znb ----------------
// PROVEN round-3 structure: half-wave (32 lanes x 4B) covers a full 128B fp8 row;
// lanes 0-31 take even edges, 32-63 odd; shfl_xor(.,32) combine. VGPR 32, LDS 2KB.
__global__ __launch_bounds__(256) void k_aggpool(const unsigned char* __restrict__ xws8,
                                                 const int* __restrict__ nstart, const int* __restrict__ cnt,
                                                 const float* __restrict__ dinv, const float* __restrict__ b_gcn,
                                                 const float* __restrict__ bn_g, const float* __restrict__ bn_b,
                                                 const int* __restrict__ ebuf2,
                                                 const float* __restrict__ lnpre_g, const float* __restrict__ lnpre_b,
                                                 float* __restrict__ h, unsigned short* __restrict__ hb,
                                                 float* __restrict__ z, float* __restrict__ zn,
                                                 unsigned short* __restrict__ znb){
    __shared__ float zacc[4][128];
    int t = threadIdx.x;
    int lane = t & 63, w = t >> 6;
    int half = lane >> 5, lh = lane & 31;
    int g = blockIdx.x;
    const unsigned int* xw32 = (const unsigned int*)xws8;   // row stride = 32 uints
    unsigned int* hb32 = (unsigned int*)hb;
    unsigned int* znb32 = (unsigned int*)znb;

    float4 bg4  = *(const float4*)&b_gcn[4*lh];
    float4 bng4 = *(const float4*)&bn_g[4*lh];
    float4 bnb4 = *(const float4*)&bn_b[4*lh];
    const float bns = rsqrtf(1.f + 1e-5f);

    float za0=0.f, za1=0.f, za2=0.f, za3=0.f;

    for (int i = w; i < 50; i += 4){
        int node = g*50 + i;
        int s0n = nstart[node]; int dg = cnt[node]; float dv = dinv[node];
        unsigned int us = xw32[node*32 + lh];   // self-loop, issued early
        float a0=0.f, a1=0.f, a2=0.f, a3=0.f;
        int j=0;
        for (; j+8<=dg; j+=8){
            int r0 = ebuf2[s0n+j+0+half];
            int r1 = ebuf2[s0n+j+2+half];
            int r2 = ebuf2[s0n+j+4+half];
            int r3 = ebuf2[s0n+j+6+half];
            unsigned int u0 = xw32[r0 + lh];
            unsigned int u1 = xw32[r1 + lh];
            unsigned int u2 = xw32[r2 + lh];
            unsigned int u3 = xw32[r3 + lh];
            f32x2 l0 = __builtin_amdgcn_cvt_pk_f32_fp8(u0, false);
            f32x2 h0 = __builtin_amdgcn_cvt_pk_f32_fp8(u0, true);
            f32x2 l1 = __builtin_amdgcn_cvt_pk_f32_fp8(u1, false);
            f32x2 h1 = __builtin_amdgcn_cvt_pk_f32_fp8(u1, true);
            f32x2 l2 = __builtin_amdgcn_cvt_pk_f32_fp8(u2, false);
            f32x2 h2 = __builtin_amdgcn_cvt_pk_f32_fp8(u2, true);
            f32x2 l3 = __builtin_amdgcn_cvt_pk_f32_fp8(u3, false);
            f32x2 h3 = __builtin_amdgcn_cvt_pk_f32_fp8(u3, true);
            a0 += (l0.x + l1.x) + (l2.x + l3.x);
            a1 += (l0.y + l1.y) + (l2.y + l3.y);
            a2 += (h0.x + h1.x) + (h2.x + h3.x);
            a3 += (h0.y + h1.y) + (h2.y + h3.y);
        }
        for (; j+2<=dg; j+=2){
            int r0 = ebuf2[s0n+j+half];
            unsigned int u0 = xw32[r0 + lh];
            f32x2 l0 = __builtin_amdgcn_cvt_pk_f32_fp8(u0, false);
            f32x2 h0 = __builtin_amdgcn_cvt_pk_f32_fp8(u0, true);
            a0 += l0.x; a1 += l0.y; a2 += h0.x; a3 += h0.y;
        }
        if (j < dg && half == 0){
            int r0 = ebuf2[s0n+j];
            unsigned int u0 = xw32[r0 + lh];
            f32x2 l0 = __builtin_amdgcn_cvt_pk_f32_fp8(u0, false);
            f32x2 h0 = __builtin_amdgcn_cvt_pk_f32_fp8(u0, true);
            a0 += l0.x; a1 += l0.y; a2 += h0.x; a3 += h0.y;
        }
        a0 += __shfl_xor(a0, 32);
        a1 += __shfl_xor(a1, 32);
        a2 += __shfl_xor(a2, 32);
        a3 += __shfl_xor(a3, 32);
        f32x2 fl = __builtin_amdgcn_cvt_pk_f32_fp8(us, false);
        f32x2 fh = __builtin_amdgcn_cvt_pk_f32_fp8(us, true);
        float p0 = dv*(a0 + 2.f*fl.x) + bg4.x;
        float p1 = dv*(a1 + 2.f*fl.y) + bg4.y;
        float p2 = dv*(a2 + 2.f*fh.x) + bg4.z;
        float p3 = dv*(a3 + 2.f*fh.y) + bg4.w;
        p0 = fmaxf(p0*bns*bng4.x + bnb4.x, 0.f);
        p1 = fmaxf(p1*bns*bng4.y + bnb4.y, 0.f);
        p2 = fmaxf(p2*bns*bng4.z + bnb4.z, 0.f);
        p3 = fmaxf(p3*bns*bng4.w + bnb4.w, 0.f);
        if (half == 0){
            *(float4*)&h[(size_t)node*F + 4*lh] = make_float4(p0,p1,p2,p3);
            *(uint2*)&hb32[(size_t)node*64 + 2*lh] = make_uint2(pk2(p0,p1), pk2(p2,p3));
        }
        za0 += p0; za1 += p1; za2 += p2; za3 += p3;
    }
    if (half == 0)
        *(float4*)&zacc[w][4*lh] = make_float4(za0, za1, za2, za3);
    __syncthreads();
    if (w == 0){
        float4 v0 = *(const float4*)&zacc[0][4*lh];
        float4 v1 = *(const float4*)&zacc[1][4*lh];
        float4 v2 = *(const float4*)&zacc[2][4*lh];
        float4 v3 = *(const float4*)&zacc[3][4*lh];
        float s0 = ((v0.x+v1.x)+(v2.x+v3.x)) / 50.0f;
        float s1 = ((v0.y+v1.y)+(v2.y+v3.y)) / 50.0f;
        float s2 = ((v0.z+v1.z)+(v2.z+v3.z)) / 50.0f;
        float s3 = ((v0.w+v1.w)+(v2.w+v3.w)) / 50.0f;
        if (half == 0)
            *(float4*)&z[(size_t)g*F + 4*lh] = make_float4(s0,s1,s2,s3);
        float s = (s0+s1)+(s2+s3);
        #pragma unroll
        for (int off=1; off<32; off<<=1) s += __shfl_xor(s, off);
        float m = s * (1.f/128.f);
        float d0=s0-m, d1=s1-m, d2=s2-m, d3=s3-m;
        float vv = (d0*d0+d1*d1)+(d2*d2+d3*d3);
        #pragma unroll
        for (int off=1; off<32; off<<=1) vv += __shfl_xor(vv, off);
        float rs = rsqrtf(vv*(1.f/128.f) + 1e-5f);
        float4 lg = *(const float4*)&lnpre_g[4*lh];
        float4 lb = *(const float4*)&lnpre_b[4*lh];
        if (half == 0){
            float o0 = d0*rs*lg.x+lb.x, o1 = d1*rs*lg.y+lb.y;
            float o2 = d2*rs*lg.z+lb.z, o3 = d3*rs*lg.w+lb.w;
            *(float4*)&zn[(size_t)g*F + 4*lh] = make_float4(o0,o1,o2,o3);
            *(uint2*)&znb32[(size_t)g*64 + 2*lh] = make_uint2(pk2(o0,o1), pk2(o2,o3));
        }
    }
}

// ---------------- generic bf16-MFMA GEMM, 128x128 tile, gate-verified fragment layout ----------------
// C = A[M,K]bf16 @ B[K,N]f32(->bf16) [+bias][ReLU]; SPLITK: z-th 128-chunk of K -> fp32 part, no bias.
template<int RELU, int BF16OUT, int SPLITK>
__global__ __launch_bounds__(256) void k_mm_bf16(const unsigned short* __restrict__ A,
                                                 const float* __restrict__ B, const float* __restrict__ bias,
                                                 float* __restrict__ Cf, unsigned short* __restrict__ Cb,
                                                 int M, int K, int Nc){
    __shared__ short Bw[128*136];
    int t = threadIdx.x;
    int rowBase = blockIdx.x*128;
    int colBase = blockIdx.y*128;
    int kbeg = SPLITK ? blockIdx.z*128 : 0;
    #pragma unroll
    for (int i=0;i<64;i++){
        int id = i*256+t; int k = id>>7, n = id&127;
        Bw[n*136 + k] = f2bs(B[(size_t)(kbeg+k)*Nc + colBase + n]);
    }
    __syncthreads();
    int lane = t & 63, w = t >> 6;
    int lr = lane & 15, quad = lane >> 4;
    int mrow0 = rowBase + w*32;
    f32x4 acc[2][8];
    #pragma unroll
    for (int i=0;i<2;i++)
        #pragma unroll
        for (int j=0;j<8;j++) acc[i][j] = (f32x4){0.f,0.f,0.f,0.f};
    #pragma unroll
    for (int ks=0; ks<4; ++ks){
        int kb = ks*32 + quad*8;
        short8 a[2];
        #pragma unroll
        for (int mt=0; mt<2; ++mt){
            int row = mrow0 + mt*16 + lr;
            if (row >= M) row = M-1;
            a[mt] = *(const short8*)&A[(size_t)row*K + kbeg + kb];
        }
        #pragma unroll
        for (int nt=0; nt<8; ++nt){
            short8 b = *(const short8*)&Bw[(nt*16 + lr)*136 + kb];
            acc[0][nt] = __builtin_amdgcn_mfma_f32_16x16x32_bf16(a[0], b, acc[0][nt], 0, 0, 0);
            acc[1][nt] = __builtin_amdgcn_mfma_f32_16x16x32_bf16(a[1], b, acc[1][nt], 0, 0, 0);
        }
    }
    #pragma unroll
    for (int mt=0; mt<2; ++mt){
        #pragma unroll
        for (int r=0; r<4; ++r){
            int row = mrow0 + mt*16 + quad*4 + r;
            if (row >= M) continue;
            #pragma unroll
            for (int nt=0; nt<8; ++nt){
                int col = colBase + nt*16 + lr;
                float v = acc[mt][nt][r];
                if (!SPLITK){
                    v += bias[col];
                    if (RELU) v = fmaxf(v, 0.f);
                    if (BF16OUT) Cb[(size_t)row*Nc + col] = (unsigned short)f2bs(v);
                    else         Cf[(size_t)row*Nc + col] = v;
                } else {
                    Cf[(size_t)blockIdx.z*M*Nc + (size_t)row*Nc + col] = v;
                }
            }
        }
    }
}

// ---------------- QKV via bf16 MFMA (blockIdx.z selects weights), fp32 out ----------------
__global__ __launch_bounds__(256) void k_qkv_mfma(const unsigned short* __restrict__ A,
                                                  const float* __restrict__ Wq, const float* __restrict__ Wk,
                                                  const float* __restrict__ Wv, const float* __restrict__ bq,
                                                  const float* __restrict__ bk, const float* __restrict__ bv,
                                                  float* __restrict__ Cq, float* __restrict__ Ck,
                                                  float* __restrict__ Cv){
    __shared__ short Bw[128*136];
    int t = threadIdx.x;
    int zsel = blockIdx.z;
    const float* B = (zsel==0) ? Wq : (zsel==1) ? Wk : Wv;
    const float* bias = (zsel==0) ? bq : (zsel==1) ? bk : bv;
    float* C = (zsel==0) ? Cq : (zsel==1) ? Ck : Cv;
    int rowBase = blockIdx.x*128;
    #pragma unroll
    for (int i=0;i<64;i++){
        int id = i*256+t; int k = id>>7, n = id&127;
        Bw[n*136 + k] = f2bs(B[(size_t)k*F + n]);
    }
    __syncthreads();
    int lane = t & 63, w = t >> 6;
    int lr = lane & 15, quad = lane >> 4;
    int mrow0 = rowBase + w*32;
    f32x4 acc[2][8];
    #pragma unroll
    for (int i=0;i<2;i++)
        #pragma unroll
        for (int j=0;j<8;j++) acc[i][j] = (f32x4){0.f,0.f,0.f,0.f};
    #pragma unroll
    for (int ks=0; ks<4; ++ks){
        int kb = ks*32 + quad*8;
        short8 a[2];
        #pragma unroll
        for (int mt=0; mt<2; ++mt){
            int row = mrow0 + mt*16 + lr;
            if (row >= NG) row = NG-1;
            a[mt] = *(const short8*)&A[(size_t)row*F + kb];
        }
        #pragma unroll
        for (int nt=0; nt<8; ++nt){
            short8 b = *(const short8*)&Bw[(nt*16 + lr)*136 + kb];
            acc[0][nt] = __builtin_amdgcn_mfma_f32_16x16x32_bf16(a[0], b, acc[0][nt], 0, 0, 0);
            acc[1][nt] = __builtin_amdgcn_mfma_f32_16x16x32_bf16(a[1], b, acc[1][nt], 0, 0, 0);
        }
    }
    #pragma unroll
    for (int mt=0; mt<2; ++mt){
        #pragma unroll
        for (int r=0; r<4; ++r){
            int row = mrow0 + mt*16 + quad*4 + r;
            if (row >= NG) continue;
            #pragma unroll
            for (int nt=0; nt<8; ++nt){
                int col = nt*16 + lr;
                C[(size_t)row*F + col] = acc[mt][nt][r] + bias[col];
            }
        }
    }
}

// ---------------- fused: ap = ao@Wo + bo; zd1 = LN(z + ap) (+ bf16 sidecar zd1b) ----------------
__global__ __launch_bounds__(256) void k_wo_ln(const float* __restrict__ ao, const float* __restrict__ Wo,
                                               const float* __restrict__ bo, const float* __restrict__ z,
                                               const float* __restrict__ g, const float* __restrict__ b,
                                               float* __restrict__ zd1, unsigned short* __restrict__ zd1b){
    __shared__ float As[32*36];
    __shared__ float Bs[32*128];
    int t = threadIdx.x;
    int rowBase = blockIdx.x*32;
    int c0 = (t&31)*4, r0 = (t>>5)*4;
    unsigned int* zd1b32 = (unsigned int*)zd1b;
    float acc[4][4];
    #pragma unroll
    for (int i=0;i<4;i++){ acc[i][0]=0.f; acc[i][1]=0.f; acc[i][2]=0.f; acc[i][3]=0.f; }
    for (int kb=0; kb<F; kb+=32){
        #pragma unroll
        for (int i=0;i<4;i++){
            int id = i*256+t; int kk = id&31; int r = id>>5;
            int row = rowBase + r;
            As[kk*36+r] = (row<NG) ? ao[(size_t)row*F + kb + kk] : 0.f;
        }
        #pragma unroll
        for (int i=0;i<16;i++){
            int id = i*256+t; int c = id&127; int kk = id>>7;
            Bs[kk*128+c] = Wo[(size_t)(kb+kk)*F + c];
        }
        __syncthreads();
        for (int kk=0;kk<32;kk++){
            float4 a = *(const float4*)&As[kk*36+r0];
            float4 bv = *(const float4*)&Bs[kk*128+c0];
            float av[4]={a.x,a.y,a.z,a.w}; float bb[4]={bv.x,bv.y,bv.z,bv.w};
            #pragma unroll
            for(int i=0;i<4;i++)
                #pragma unroll
                for(int j=0;j<4;j++) acc[i][j] += av[i]*bb[j];
        }
        __syncthreads();
    }
    float4 bo4 = *(const float4*)&bo[c0];
    float4 g4  = *(const float4*)&g[c0];
    float4 b4  = *(const float4*)&b[c0];
    #pragma unroll
    for (int i=0;i<4;i++){
        int row = rowBase + r0 + i;
        float v0=0.f,v1=0.f,v2=0.f,v3=0.f;
        if (row < NG){
            float4 zr = *(const float4*)&z[(size_t)row*F + c0];
            v0 = acc[i][0] + bo4.x + zr.x;
            v1 = acc[i][1] + bo4.y + zr.y;
            v2 = acc[i][2] + bo4.z + zr.z;
            v3 = acc[i][3] + bo4.w + zr.w;
        }
        float s = (v0+v1)+(v2+v3);
        #pragma unroll
        for (int off=1; off<32; off<<=1) s += __shfl_xor(s, off);
        float m = s * (1.f/128.f);
        float d0=v0-m, d1=v1-m, d2=v2-m, d3=v3-m;
        float vv = (d0*d0+d1*d1)+(d2*d2+d3*d3);
        #pragma unroll
        for (int off=1; off<32; off<<=1) vv += __shfl_xor(vv, off);
        float rs = rsqrtf(vv*(1.f/128.f) + 1e-5f);
        if (row < NG){
            float o0 = d0*rs*g4.x+b4.x, o1 = d1*rs*g4.y+b4.y;
            float o2 = d2*rs*g4.z+b4.z, o3 = d3*rs*g4.w+b4.w;
            *(float4*)&zd1[(size_t)row*F + c0] = make_float4(o0,o1,o2,o3);
            *(uint2*)&zd1b32[(size_t)row*(F/2) + c0/2] = make_uint2(pk2(o0,o1), pk2(o2,o3));
        }
    }
}

// ---------------- fused: zd2 = LN(zd1 + sum(part) + b2); gsi = zd2 @ Wg_bot + bg ----------------
__global__ __launch_bounds__(256) void k_ln_red_gsi(const float* __restrict__ A, const float* __restrict__ part,
                                                    const float* __restrict__ bias, const float* __restrict__ g,
                                                    const float* __restrict__ b, const float* __restrict__ Wb,
                                                    const float* __restrict__ bg, float* __restrict__ zd2,
                                                    float* __restrict__ gsi){
    __shared__ float Zs[4][128];
    __shared__ float Bs[32*128];
    int t = threadIdx.x; int lane = t&63;
    int rquad = t>>6;
    int row = blockIdx.x*4 + rquad;
    int i0 = row*F + 2*lane;
    float x0 = A[i0] + bias[2*lane], x1 = A[i0+1] + bias[2*lane+1];
    #pragma unroll
    for (int zz=0; zz<KSPLIT; ++zz){
        x0 += part[(size_t)zz*NG*F + i0];
        x1 += part[(size_t)zz*NG*F + i0 + 1];
    }
    float s = x0+x1;
    for (int off=1; off<64; off<<=1) s += __shfl_xor(s, off);
    float m = s * (1.f/128.f);
    float d0 = x0-m, d1 = x1-m;
    float vv = d0*d0 + d1*d1;
    for (int off=1; off<64; off<<=1) vv += __shfl_xor(vv, off);
    float rs = rsqrtf(vv*(1.f/128.f) + 1e-5f);
    float o0 = d0*rs*g[2*lane]   + b[2*lane];
    float o1 = d1*rs*g[2*lane+1] + b[2*lane+1];
    zd2[i0]   = o0;
    zd2[i0+1] = o1;
    Zs[rquad][2*lane]   = o0;
    Zs[rquad][2*lane+1] = o1;
    __syncthreads();
    int col = t & 127, rp = t >> 7;
    float a0=0.f, a1=0.f;
    for (int kb=0; kb<F; kb+=32){
        #pragma unroll
        for (int i=0;i<16;i++){
            int id = i*256+t; int c = id&127; int kk = id>>7;
            Bs[kk*128+c] = Wb[(size_t)(kb+kk)*F + c];
        }
        __syncthreads();
        for (int kk=0;kk<32;kk++){
            float w = Bs[kk*128+col];
            a0 += Zs[rp][kb+kk]   * w;
            a1 += Zs[rp+2][kb+kk] * w;
        }
        __syncthreads();
    }
    float bgc = bg[col];
    gsi[(size_t)(blockIdx.x*4 + rp)*F + col]     = a0 + bgc;
    gsi[(size_t)(blockIdx.x*4 + rp + 2)*F + col] = a1 + bgc;
}

// ---------------- attention: one block per (set, head) ----------------
__global__ __launch_bounds__(256) void k_attn(const float* __restrict__ q, const float* __restrict__ k,
                                              const float* __restrict__ v, float* __restrict__ o){
    __shared__ float Qs[1600], Ks[1600], Vs[1600], Sc[2500];
    int t = threadIdx.x;
    int s = blockIdx.x >> 2; int hh = blockIdx.x & 3;
    for (int idx=t; idx<1600; idx+=256){
        int i = idx>>5, d = idx&31;
        size_t gi = (size_t)(s*50+i)*F + hh*32 + d;
        Qs[idx]=q[gi]; Ks[idx]=k[gi]; Vs[idx]=v[gi];
    }
    __syncthreads();
    for (int idx=t; idx<2500; idx+=256){
        int qi = idx/50, ki = idx%50;
        float acc=0.f;
        #pragma unroll 8
        for (int d=0;d<32;d++) acc += Qs[qi*32+d]*Ks[ki*32+d];
        Sc[idx] = acc * 0.17677669529663687f;   // 1/sqrt(32)
    }
    __syncthreads();
    if (t < 50){
        float m=-1e30f;
        for (int j=0;j<50;j++) m = fmaxf(m, Sc[t*50+j]);
        float sum=0.f;
        for (int j=0;j<50;j++){ float e=__expf(Sc[t*50+j]-m); Sc[t*50+j]=e; sum+=e; }
        float inv = 1.f/sum;
        for (int j=0;j<50;j++) Sc[t*50+j] *= inv;
    }
    __syncthreads();
    for (int idx=t; idx<1600; idx+=256){
        int qi = idx>>5, d = idx&31;
        float acc=0.f;
        #pragma unroll 10
        for (int ki=0;ki<50;ki++) acc += Sc[qi*50+ki]*Vs[ki*32+d];
        o[(size_t)(s*50+qi)*F + hh*32 + d] = acc;
    }
}

// ---------------- MFMA gate: L = h @ Wg_top (bf16 MFMA), out = sig(L+gsi)*zd2 + (1-sig)*h ----------------
__global__ __launch_bounds__(256) void k_gate_mfma(const float* __restrict__ h,
                                                   const unsigned short* __restrict__ hb,
                                                   const float* __restrict__ Wg,
                                                   const float* __restrict__ gsi, const float* __restrict__ zd2,
                                                   float* __restrict__ out){
    __shared__ short Bw[128*136];   // Wg_top^T as bf16, [n][k]
    int t = threadIdx.x;
    for (int i=t; i<16384; i+=256){
        int k = i >> 7, n = i & 127;
        Bw[n*136 + k] = f2bs(Wg[(size_t)k*F + n]);
    }
    __syncthreads();
    int lane = t & 63, w = t >> 6;
    int lr = lane & 15, quad = lane >> 4;
    int mrow0 = blockIdx.x*128 + w*32;
    f32x4 acc[2][8];
    #pragma unroll
    for (int i=0;i<2;i++)
        #pragma unroll
        for (int j=0;j<8;j++) acc[i][j] = (f32x4){0.f,0.f,0.f,0.f};
    #pragma unroll
    for (int ks=0; ks<4; ++ks){
        int kb = ks*32 + quad*8;
        short8 a[2];
        #pragma unroll
        for (int mt=0; mt<2; ++mt){
            int row = mrow0 + mt*16 + lr;
            if (row >= NN) row = NN-1;
            a[mt] = *(const short8*)&hb[(size_t)row*F + kb];
        }
        #pragma unroll
        for (int nt=0; nt<8; ++nt){
            short8 b = *(const short8*)&Bw[(nt*16 + lr)*136 + kb];
            acc[0][nt] = __builtin_amdgcn_mfma_f32_16x16x32_bf16(a[0], b, acc[0][nt], 0, 0, 0);
            acc[1][nt] = __builtin_amdgcn_mfma_f32_16x16x32_bf16(a[1], b, acc[1][nt], 0, 0, 0);
        }
    }
    #pragma unroll
    for (int mt=0; mt<2; ++mt){
        #pragma unroll
        for (int r=0; r<4; ++r){
            int row = mrow0 + mt*16 + quad*4 + r;
            if (row >= NN) continue;
            int g = row / 50;
            const float* gs = &gsi[(size_t)g*F];
            const float* zs = &zd2[(size_t)g*F];
            const float* hr = &h[(size_t)row*F];
            float* orow = &out[(size_t)row*F];
            #pragma unroll
            for (int nt=0; nt<8; ++nt){
                int col = nt*16 + lr;
                float L = acc[mt][nt][r] + gs[col];
                float gate = 1.f/(1.f + __expf(-L));
                orow[col] = gate*zs[col] + (1.f-gate)*hr[col];
            }
        }
    }
}

extern "C" void kernel_launch(void* const* d_in, const int* in_sizes, int n_in,
                              void* d_out, int out_size, void* d_ws, size_t ws_size,
                              hipStream_t stream) {
    const float* x      = (const float*)d_in[0];
    const int*   ei     = (const int*)d_in[1];
    const float* W_gcn  = (const float*)d_in[4];
    const float* b_gcn  = (const float*)d_in[5];
    const float* bn_g   = (const float*)d_in[6];
    const float* bn_b   = (const float*)d_in[7];
    const float* lnpre_g= (const float*)d_in[8];
    const float* lnpre_b= (const float*)d_in[9];
    const float* Wq     = (const float*)d_in[10];
    const float* bq     = (const float*)d_in[11];
    const float* Wk     = (const float*)d_in[12];
    const float* bk     = (const float*)d_in[13];
    const float* Wv     = (const float*)d_in[14];
    const float* bv     = (const float*)d_in[15];
    const float* Wo     = (const float*)d_in[16];
    const float* bo     = (const float*)d_in[17];
    const float* ln1_g  = (const float*)d_in[18];
    const float* ln1_b  = (const float*)d_in[19];
    const float* W1     = (const float*)d_in[20];
    const float* b1     = (const float*)d_in[21];
    const float* W2     = (const float*)d_in[22];
    const float* b2     = (const float*)d_in[23];
    const float* ln2_g  = (const float*)d_in[24];
    const float* ln2_b  = (const float*)d_in[25];
    const float* Wg     = (const float*)d_in[26];
    const float* bg     = (const float*)d_in[27];
    float* out = (float*)d_out;
    char* ws = (char*)d_ws;

    // workspace layout
    size_t o = 0;
    unsigned char* xws8 = (unsigned char*)(ws + o); o += (size_t)NN*F; // 12.8 MB (fp8)
    float* h     = (float*)(ws + o); o += (size_t)NN*F*4;            // 51.2 MB
    unsigned short* hb = (unsigned short*)(ws + o); o += (size_t)NN*F*2; // 25.6 MB (bf16)
    int*   cnt   = (int*)(ws + o);   o += (size_t)NN*4;
    int*   nstart= (int*)(ws + o);   o += (size_t)NN*4;
    int*   ebuf  = (int*)(ws + o);   o += (size_t)NB*BCAP*4;         // 9.6 MB
    int*   ebuf2 = (int*)(ws + o);   o += (size_t)NB*BCAP*4;         // 9.6 MB
    float* dinv  = (float*)(ws + o); o += (size_t)NN*4;
    int*   bcursor=(int*)(ws + o);   o += 1024*4;
    float* z     = (float*)(ws + o); o += (size_t)NG*F*4;
    float* zn    = (float*)(ws + o); o += (size_t)NG*F*4;
    unsigned short* znb = (unsigned short*)(ws + o); o += (size_t)NG*F*2;
    float* qb    = (float*)(ws + o); o += (size_t)NG*F*4;
    float* kb2   = (float*)(ws + o); o += (size_t)NG*F*4;
    float* vb    = (float*)(ws + o); o += (size_t)NG*F*4;
    float* ao    = (float*)(ws + o); o += (size_t)NG*F*4;
    float* zd1   = (float*)(ws + o); o += (size_t)NG*F*4;
    unsigned short* zd1b = (unsigned short*)(ws + o); o += (size_t)NG*F*2;
    unsigned short* ffn1b = (unsigned short*)(ws + o); o += (size_t)NG*FFN_DIM*2; // 4.1 MB
    float* part  = (float*)(ws + o); o += (size_t)KSPLIT*NG*F*4;     // 8.2 MB
    float* zd2   = (float*)(ws + o); o += (size_t)NG*F*4;
    float* gsi   = (float*)(ws + o); o += (size_t)NG*F*4;

    // ---- GCN phase ----
    k_binit<<<1, 1024, 0, stream>>>(bcursor);
    k_scatter2<<<SC_BLOCKS, 1024, 0, stream>>>(ei, bcursor, ebuf);
    k_sort<<<NB, 256, 0, stream>>>(ebuf, bcursor, cnt, dinv, nstart, ebuf2);
    k_xws<<<(NN+127)/128, 256, 0, stream>>>(x, W_gcn, dinv, xws8);
    k_aggpool<<<NG, 256, 0, stream>>>(xws8, nstart, cnt, dinv, b_gcn, bn_g, bn_b, ebuf2,
                                      lnpre_g, lnpre_b, h, hb, z, zn, znb);

    // ---- set transformer (bf16 MFMA GEMMs, fp32 LN/attn) ----
    dim3 gqkv((NG+127)/128, 1, 3);
    k_qkv_mfma<<<gqkv, 256, 0, stream>>>(znb, Wq, Wk, Wv, bq, bk, bv, qb, kb2, vb);
    k_attn<<<NS*4, 256, 0, stream>>>(qb, kb2, vb, ao);
    k_wo_ln<<<(NG+31)/32, 256, 0, stream>>>(ao, Wo, bo, z, ln1_g, ln1_b, zd1, zd1b);
    dim3 gffn1((NG+127)/128, FFN_DIM/128, 1);
    k_mm_bf16<1,1,0><<<gffn1, 256, 0, stream>>>(zd1b, W1, b1, nullptr, ffn1b, NG, F, FFN_DIM);
    dim3 gffn2((NG+127)/128, 1, KSPLIT);
    k_mm_bf16<0,0,1><<<gffn2, 256, 0, stream>>>(ffn1b, W2, nullptr, part, nullptr, NG, FFN_DIM, F);
    k_ln_red_gsi<<<NG/4, 256, 0, stream>>>(zd1, part, b2, ln2_g, ln2_b,
                                           Wg + (size_t)F*F, bg, zd2, gsi);

    // ---- gated fusion -> output ----
    k_gate_mfma<<<782, 256, 0, stream>>>(h, hb, Wg, gsi, zd2, out);
}

// Round 7
// 351.904 us; speedup vs baseline: 1.0362x; 1.0061x over previous
//
#include <hip/hip_runtime.h>
#include <hip/hip_bf16.h>
#include <cstddef>

#define NN 100000
#define NE 1600000
#define NG 2000
#define NS 40
#define INF 64
#define F 128
#define FFN_DIM 1024
#define NB 782            // ceil(100000/128) buckets of 128 nodes
#define BCAP 3072         // fixed bucket capacity (mean 2048, sigma 45 -> 19+ sigma margin)
#define SC_BLOCKS 512
#define SC_CHUNK 3125     // 512*3125 = 1.6M edges exactly
#define KSPLIT 8

using bf16 = __hip_bfloat16;
typedef __attribute__((ext_vector_type(8))) short short8;
typedef __attribute__((ext_vector_type(4))) float f32x4;
typedef __attribute__((ext_vector_type(2))) float f32x2;

__device__ __forceinline__ short f2bs(float f){
    union { bf16 b; short s; } u; u.b = __float2bfloat16(f); return u.s;
}
__device__ __forceinline__ unsigned int pk2(float a, float b){
    return (unsigned int)(unsigned short)f2bs(a) | ((unsigned int)(unsigned short)f2bs(b) << 16);
}

// ---------------- init bucket cursors to fixed region starts ----------------
__global__ __launch_bounds__(1024) void k_binit(int* __restrict__ bcursor){
    int t = threadIdx.x;
    if (t < NB) bcursor[t] = t * BCAP;
}

// ---------------- Wgb[n*128+k] = bf16(Wg_top[k][n]) — one-time 32KB transpose+convert ----------------
__global__ __launch_bounds__(256) void k_wcvt(const float* __restrict__ Wg, unsigned short* __restrict__ Wgb){
    int t = blockIdx.x*256 + threadIdx.x;
    for (int i=t; i<16384; i+=16*256){
        int k = i >> 7, n = i & 127;
        Wgb[n*128 + k] = (unsigned short)f2bs(Wg[(size_t)k*F + n]);
    }
}

// ---------------- xws = (x @ W_gcn) * dinv[row], bf16 MFMA, stored fp8 e4m3 ----------------
__global__ __launch_bounds__(256) void k_xws(const float* __restrict__ x, const float* __restrict__ W,
                                             const float* __restrict__ dinv, unsigned char* __restrict__ xws8){
    __shared__ short Xs[128*72];   // [row][k], stride 72
    __shared__ short Ws[128*72];   // [feature][k], stride 72
    int t = threadIdx.x;
    int rowBase = blockIdx.x * 128;
    #pragma unroll
    for (int i=0;i<32;i++){
        int id = i*256+t; int k = id>>7, n = id&127;
        Ws[n*72 + k] = f2bs(W[id]);
    }
    #pragma unroll
    for (int i=0;i<8;i++){
        int id = i*256+t;              // 2048 float4 slots
        int r = id>>4; int k4 = (id&15)*4;
        int row = rowBase + r; if (row >= NN) row = NN-1;
        float4 v = *(const float4*)&x[(size_t)row*INF + k4];
        *(unsigned int*)&Xs[r*72 + k4]     = pk2(v.x, v.y);
        *(unsigned int*)&Xs[r*72 + k4 + 2] = pk2(v.z, v.w);
    }
    __syncthreads();
    int lane = t & 63, w = t >> 6;
    int lr = lane & 15, quad = lane >> 4;
    f32x4 acc[2][8];
    #pragma unroll
    for (int i=0;i<2;i++)
        #pragma unroll
        for (int j=0;j<8;j++) acc[i][j] = (f32x4){0.f,0.f,0.f,0.f};
    #pragma unroll
    for (int ks=0; ks<2; ++ks){
        int kb = ks*32 + quad*8;
        short8 b0 = *(const short8*)&Xs[((w  )*16 + lr)*72 + kb];
        short8 b1 = *(const short8*)&Xs[((w+4)*16 + lr)*72 + kb];
        #pragma unroll
        for (int mt=0; mt<8; ++mt){
            short8 a = *(const short8*)&Ws[(mt*16 + lr)*72 + kb];
            acc[0][mt] = __builtin_amdgcn_mfma_f32_16x16x32_bf16(a, b0, acc[0][mt], 0, 0, 0);
            acc[1][mt] = __builtin_amdgcn_mfma_f32_16x16x32_bf16(a, b1, acc[1][mt], 0, 0, 0);
        }
    }
    #pragma unroll
    for (int rt=0; rt<2; ++rt){
        int row = rowBase + (w + rt*4)*16 + lr;
        if (row < NN){
            float dv = dinv[row];
            #pragma unroll
            for (int mt=0; mt<8; ++mt){
                int p = __builtin_amdgcn_cvt_pk_fp8_f32(acc[rt][mt][0]*dv, acc[rt][mt][1]*dv, 0, false);
                p     = __builtin_amdgcn_cvt_pk_fp8_f32(acc[rt][mt][2]*dv, acc[rt][mt][3]*dv, p, true);
                *(int*)&xws8[(size_t)row*F + mt*16 + quad*4] = p;
            }
        }
    }
}

// ---------------- binned scatter: pack (row<<7|col&127) into fixed bucket regions ----------------
__global__ __launch_bounds__(1024) void k_scatter2(const int* __restrict__ ei, int* __restrict__ bcursor,
                                                   int* __restrict__ ebuf){
    __shared__ int lh[NB];
    __shared__ int lb[NB];
    int t = threadIdx.x;
    int base = blockIdx.x * SC_CHUNK;
    for (int b=t; b<NB; b+=1024) lh[b] = 0;
    __syncthreads();
    int rr[4], cc[4];
    #pragma unroll
    for (int q=0;q<4;q++){
        int i = t + q*1024;
        bool v = (i < SC_CHUNK);
        int idx = v ? (base + i) : base;
        rr[q] = ei[idx];
        cc[q] = ei[NE + idx];
        if (v) atomicAdd(&lh[cc[q]>>7], 1);
    }
    __syncthreads();
    for (int b=t; b<NB; b+=1024){
        int n = lh[b];
        lb[b] = n ? atomicAdd(&bcursor[b], n) : 0;
        lh[b] = 0;
    }
    __syncthreads();
    #pragma unroll
    for (int q=0;q<4;q++){
        int i = t + q*1024;
        if (i < SC_CHUNK){
            int b = cc[q] >> 7;
            int rk = atomicAdd(&lh[b], 1);
            ebuf[lb[b] + rk] = (rr[q] << 7) | (cc[q] & 127);
        }
    }
}

// ---------------- per-bucket counting sort; emits PRE-MULTIPLIED word offsets ----------------
__global__ __launch_bounds__(256) void k_sort(const int* __restrict__ ebuf, const int* __restrict__ bcursor,
                                              int* __restrict__ cnt, float* __restrict__ dinv,
                                              int* __restrict__ nstart, int* __restrict__ ebuf2){
    __shared__ int lh[128];
    __shared__ int s[128];
    __shared__ int lcur[128];
    int t = threadIdx.x;
    int b = blockIdx.x;
    int e0 = b * BCAP;
    int nE = bcursor[b] - e0;
    if (t < 128) lh[t] = 0;
    __syncthreads();
    for (int i=t; i<nE; i+=256) atomicAdd(&lh[ebuf[e0+i] & 127], 1);
    __syncthreads();
    int c = (t < 128) ? lh[t] : 0;
    if (t < 128) s[t] = c;
    __syncthreads();
    #pragma unroll
    for (int off=1; off<128; off<<=1){
        int v = (t >= off && t < 128) ? s[t-off] : 0;
        __syncthreads();
        if (t < 128) s[t] += v;
        __syncthreads();
    }
    int node = b*128 + t;
    if (t < 128){
        int excl = s[t] - c;
        lcur[t] = excl;
        if (node < NN){
            nstart[node] = e0 + excl;
            cnt[node] = c;
            dinv[node] = rsqrtf((float)c + 2.0f);
        }
    }
    __syncthreads();
    for (int i=t; i<nE; i+=256){
        int v = ebuf[e0 + i];
        int nl = v & 127;
        int rk = atomicAdd(&lcur[nl], 1);
        ebuf2[e0 + rk] = (v >> 7) << 5;   // row * 32 (uint-word offset into xws8)
    }
}

// ---------------- fused: CSR gather (2 edges/wave-load) + GCN epilogue + BN + ReLU
//                  -> h (fp32) + hb (bf16) + pool + pre-LN -> z, zn, znb ----------------
__global__ __launch_bounds__(256) void k_aggpool(const unsigned char* __restrict__ xws8,
                                                 const int* __restrict__ nstart, const int* __restrict__ cnt,
                                                 const float* __restrict__ dinv, const float* __restrict__ b_gcn,
                                                 const float* __restrict__ bn_g, const float* __restrict__ bn_b,
                                                 const int* __restrict__ ebuf2,
                                                 const float* __restrict__ lnpre_g, const float* __restrict__ lnpre_b,
                                                 float* __restrict__ h, unsigned short* __restrict__ hb,
                                                 float* __restrict__ z, float* __restrict__ zn,
                                                 unsigned short* __restrict__ znb){
    __shared__ float zacc[4][128];
    int t = threadIdx.x;
    int lane = t & 63, w = t >> 6;
    int half = lane >> 5, lh = lane & 31;
    int g = blockIdx.x;
    const unsigned int* xw32 = (const unsigned int*)xws8;   // row stride = 32 uints
    unsigned int* hb32 = (unsigned int*)hb;
    unsigned int* znb32 = (unsigned int*)znb;

    float4 bg4  = *(const float4*)&b_gcn[4*lh];
    float4 bng4 = *(const float4*)&bn_g[4*lh];
    float4 bnb4 = *(const float4*)&bn_b[4*lh];
    const float bns = rsqrtf(1.f + 1e-5f);

    float za0=0.f, za1=0.f, za2=0.f, za3=0.f;

    for (int i = w; i < 50; i += 4){
        int node = g*50 + i;
        int s0n = nstart[node]; int dg = cnt[node]; float dv = dinv[node];
        unsigned int us = xw32[node*32 + lh];   // self-loop, issued early
        float a0=0.f, a1=0.f, a2=0.f, a3=0.f;
        int j=0;
        for (; j+8<=dg; j+=8){
            int r0 = ebuf2[s0n+j+0+half];
            int r1 = ebuf2[s0n+j+2+half];
            int r2 = ebuf2[s0n+j+4+half];
            int r3 = ebuf2[s0n+j+6+half];
            unsigned int u0 = xw32[r0 + lh];
            unsigned int u1 = xw32[r1 + lh];
            unsigned int u2 = xw32[r2 + lh];
            unsigned int u3 = xw32[r3 + lh];
            f32x2 l0 = __builtin_amdgcn_cvt_pk_f32_fp8(u0, false);
            f32x2 h0 = __builtin_amdgcn_cvt_pk_f32_fp8(u0, true);
            f32x2 l1 = __builtin_amdgcn_cvt_pk_f32_fp8(u1, false);
            f32x2 h1 = __builtin_amdgcn_cvt_pk_f32_fp8(u1, true);
            f32x2 l2 = __builtin_amdgcn_cvt_pk_f32_fp8(u2, false);
            f32x2 h2 = __builtin_amdgcn_cvt_pk_f32_fp8(u2, true);
            f32x2 l3 = __builtin_amdgcn_cvt_pk_f32_fp8(u3, false);
            f32x2 h3 = __builtin_amdgcn_cvt_pk_f32_fp8(u3, true);
            a0 += (l0.x + l1.x) + (l2.x + l3.x);
            a1 += (l0.y + l1.y) + (l2.y + l3.y);
            a2 += (h0.x + h1.x) + (h2.x + h3.x);
            a3 += (h0.y + h1.y) + (h2.y + h3.y);
        }
        for (; j+2<=dg; j+=2){
            int r0 = ebuf2[s0n+j+half];
            unsigned int u0 = xw32[r0 + lh];
            f32x2 l0 = __builtin_amdgcn_cvt_pk_f32_fp8(u0, false);
            f32x2 h0 = __builtin_amdgcn_cvt_pk_f32_fp8(u0, true);
            a0 += l0.x; a1 += l0.y; a2 += h0.x; a3 += h0.y;
        }
        if (j < dg && half == 0){
            int r0 = ebuf2[s0n+j];
            unsigned int u0 = xw32[r0 + lh];
            f32x2 l0 = __builtin_amdgcn_cvt_pk_f32_fp8(u0, false);
            f32x2 h0 = __builtin_amdgcn_cvt_pk_f32_fp8(u0, true);
            a0 += l0.x; a1 += l0.y; a2 += h0.x; a3 += h0.y;
        }
        a0 += __shfl_xor(a0, 32);
        a1 += __shfl_xor(a1, 32);
        a2 += __shfl_xor(a2, 32);
        a3 += __shfl_xor(a3, 32);
        f32x2 fl = __builtin_amdgcn_cvt_pk_f32_fp8(us, false);
        f32x2 fh = __builtin_amdgcn_cvt_pk_f32_fp8(us, true);
        float p0 = dv*(a0 + 2.f*fl.x) + bg4.x;
        float p1 = dv*(a1 + 2.f*fl.y) + bg4.y;
        float p2 = dv*(a2 + 2.f*fh.x) + bg4.z;
        float p3 = dv*(a3 + 2.f*fh.y) + bg4.w;
        p0 = fmaxf(p0*bns*bng4.x + bnb4.x, 0.f);
        p1 = fmaxf(p1*bns*bng4.y + bnb4.y, 0.f);
        p2 = fmaxf(p2*bns*bng4.z + bnb4.z, 0.f);
        p3 = fmaxf(p3*bns*bng4.w + bnb4.w, 0.f);
        if (half == 0){
            *(float4*)&h[(size_t)node*F + 4*lh] = make_float4(p0,p1,p2,p3);
            *(uint2*)&hb32[(size_t)node*64 + 2*lh] = make_uint2(pk2(p0,p1), pk2(p2,p3));
        }
        za0 += p0; za1 += p1; za2 += p2; za3 += p3;
    }
    if (half == 0)
        *(float4*)&zacc[w][4*lh] = make_float4(za0, za1, za2, za3);
    __syncthreads();
    if (w == 0){
        float4 v0 = *(const float4*)&zacc[0][4*lh];
        float4 v1 = *(const float4*)&zacc[1][4*lh];
        float4 v2 = *(const float4*)&zacc[2][4*lh];
        float4 v3 = *(const float4*)&zacc[3][4*lh];
        float s0 = ((v0.x+v1.x)+(v2.x+v3.x)) / 50.0f;
        float s1 = ((v0.y+v1.y)+(v2.y+v3.y)) / 50.0f;
        float s2 = ((v0.z+v1.z)+(v2.z+v3.z)) / 50.0f;
        float s3 = ((v0.w+v1.w)+(v2.w+v3.w)) / 50.0f;
        if (half == 0)
            *(float4*)&z[(size_t)g*F + 4*lh] = make_float4(s0,s1,s2,s3);
        float s = (s0+s1)+(s2+s3);
        #pragma unroll
        for (int off=1; off<32; off<<=1) s += __shfl_xor(s, off);
        float m = s * (1.f/128.f);
        float d0=s0-m, d1=s1-m, d2=s2-m, d3=s3-m;
        float vv = (d0*d0+d1*d1)+(d2*d2+d3*d3);
        #pragma unroll
        for (int off=1; off<32; off<<=1) vv += __shfl_xor(vv, off);
        float rs = rsqrtf(vv*(1.f/128.f) + 1e-5f);
        float4 lg = *(const float4*)&lnpre_g[4*lh];
        float4 lb = *(const float4*)&lnpre_b[4*lh];
        if (half == 0){
            float o0 = d0*rs*lg.x+lb.x, o1 = d1*rs*lg.y+lb.y;
            float o2 = d2*rs*lg.z+lb.z, o3 = d3*rs*lg.w+lb.w;
            *(float4*)&zn[(size_t)g*F + 4*lh] = make_float4(o0,o1,o2,o3);
            *(uint2*)&znb32[(size_t)g*64 + 2*lh] = make_uint2(pk2(o0,o1), pk2(o2,o3));
        }
    }
}

// ---------------- generic bf16-MFMA GEMM, 128x128 tile ----------------
template<int RELU, int BF16OUT, int SPLITK>
__global__ __launch_bounds__(256) void k_mm_bf16(const unsigned short* __restrict__ A,
                                                 const float* __restrict__ B, const float* __restrict__ bias,
                                                 float* __restrict__ Cf, unsigned short* __restrict__ Cb,
                                                 int M, int K, int Nc){
    __shared__ short Bw[128*136];
    int t = threadIdx.x;
    int rowBase = blockIdx.x*128;
    int colBase = blockIdx.y*128;
    int kbeg = SPLITK ? blockIdx.z*128 : 0;
    #pragma unroll
    for (int i=0;i<64;i++){
        int id = i*256+t; int k = id>>7, n = id&127;
        Bw[n*136 + k] = f2bs(B[(size_t)(kbeg+k)*Nc + colBase + n]);
    }
    __syncthreads();
    int lane = t & 63, w = t >> 6;
    int lr = lane & 15, quad = lane >> 4;
    int mrow0 = rowBase + w*32;
    f32x4 acc[2][8];
    #pragma unroll
    for (int i=0;i<2;i++)
        #pragma unroll
        for (int j=0;j<8;j++) acc[i][j] = (f32x4){0.f,0.f,0.f,0.f};
    #pragma unroll
    for (int ks=0; ks<4; ++ks){
        int kb = ks*32 + quad*8;
        short8 a[2];
        #pragma unroll
        for (int mt=0; mt<2; ++mt){
            int row = mrow0 + mt*16 + lr;
            if (row >= M) row = M-1;
            a[mt] = *(const short8*)&A[(size_t)row*K + kbeg + kb];
        }
        #pragma unroll
        for (int nt=0; nt<8; ++nt){
            short8 b = *(const short8*)&Bw[(nt*16 + lr)*136 + kb];
            acc[0][nt] = __builtin_amdgcn_mfma_f32_16x16x32_bf16(a[0], b, acc[0][nt], 0, 0, 0);
            acc[1][nt] = __builtin_amdgcn_mfma_f32_16x16x32_bf16(a[1], b, acc[1][nt], 0, 0, 0);
        }
    }
    #pragma unroll
    for (int mt=0; mt<2; ++mt){
        #pragma unroll
        for (int r=0; r<4; ++r){
            int row = mrow0 + mt*16 + quad*4 + r;
            if (row >= M) continue;
            #pragma unroll
            for (int nt=0; nt<8; ++nt){
                int col = colBase + nt*16 + lr;
                float v = acc[mt][nt][r];
                if (!SPLITK){
                    v += bias[col];
                    if (RELU) v = fmaxf(v, 0.f);
                    if (BF16OUT) Cb[(size_t)row*Nc + col] = (unsigned short)f2bs(v);
                    else         Cf[(size_t)row*Nc + col] = v;
                } else {
                    Cf[(size_t)blockIdx.z*M*Nc + (size_t)row*Nc + col] = v;
                }
            }
        }
    }
}

// ---------------- QKV via bf16 MFMA (blockIdx.z selects weights), fp32 out ----------------
__global__ __launch_bounds__(256) void k_qkv_mfma(const unsigned short* __restrict__ A,
                                                  const float* __restrict__ Wq, const float* __restrict__ Wk,
                                                  const float* __restrict__ Wv, const float* __restrict__ bq,
                                                  const float* __restrict__ bk, const float* __restrict__ bv,
                                                  float* __restrict__ Cq, float* __restrict__ Ck,
                                                  float* __restrict__ Cv){
    __shared__ short Bw[128*136];
    int t = threadIdx.x;
    int zsel = blockIdx.z;
    const float* B = (zsel==0) ? Wq : (zsel==1) ? Wk : Wv;
    const float* bias = (zsel==0) ? bq : (zsel==1) ? bk : bv;
    float* C = (zsel==0) ? Cq : (zsel==1) ? Ck : Cv;
    int rowBase = blockIdx.x*128;
    #pragma unroll
    for (int i=0;i<64;i++){
        int id = i*256+t; int k = id>>7, n = id&127;
        Bw[n*136 + k] = f2bs(B[(size_t)k*F + n]);
    }
    __syncthreads();
    int lane = t & 63, w = t >> 6;
    int lr = lane & 15, quad = lane >> 4;
    int mrow0 = rowBase + w*32;
    f32x4 acc[2][8];
    #pragma unroll
    for (int i=0;i<2;i++)
        #pragma unroll
        for (int j=0;j<8;j++) acc[i][j] = (f32x4){0.f,0.f,0.f,0.f};
    #pragma unroll
    for (int ks=0; ks<4; ++ks){
        int kb = ks*32 + quad*8;
        short8 a[2];
        #pragma unroll
        for (int mt=0; mt<2; ++mt){
            int row = mrow0 + mt*16 + lr;
            if (row >= NG) row = NG-1;
            a[mt] = *(const short8*)&A[(size_t)row*F + kb];
        }
        #pragma unroll
        for (int nt=0; nt<8; ++nt){
            short8 b = *(const short8*)&Bw[(nt*16 + lr)*136 + kb];
            acc[0][nt] = __builtin_amdgcn_mfma_f32_16x16x32_bf16(a[0], b, acc[0][nt], 0, 0, 0);
            acc[1][nt] = __builtin_amdgcn_mfma_f32_16x16x32_bf16(a[1], b, acc[1][nt], 0, 0, 0);
        }
    }
    #pragma unroll
    for (int mt=0; mt<2; ++mt){
        #pragma unroll
        for (int r=0; r<4; ++r){
            int row = mrow0 + mt*16 + quad*4 + r;
            if (row >= NG) continue;
            #pragma unroll
            for (int nt=0; nt<8; ++nt){
                int col = nt*16 + lr;
                C[(size_t)row*F + col] = acc[mt][nt][r] + bias[col];
            }
        }
    }
}

// ---------------- fused: ap = ao@Wo + bo; zd1 = LN(z + ap) (+ bf16 sidecar zd1b) ----------------
__global__ __launch_bounds__(256) void k_wo_ln(const float* __restrict__ ao, const float* __restrict__ Wo,
                                               const float* __restrict__ bo, const float* __restrict__ z,
                                               const float* __restrict__ g, const float* __restrict__ b,
                                               float* __restrict__ zd1, unsigned short* __restrict__ zd1b){
    __shared__ float As[32*36];
    __shared__ float Bs[32*128];
    int t = threadIdx.x;
    int rowBase = blockIdx.x*32;
    int c0 = (t&31)*4, r0 = (t>>5)*4;
    unsigned int* zd1b32 = (unsigned int*)zd1b;
    float acc[4][4];
    #pragma unroll
    for (int i=0;i<4;i++){ acc[i][0]=0.f; acc[i][1]=0.f; acc[i][2]=0.f; acc[i][3]=0.f; }
    for (int kb=0; kb<F; kb+=32){
        #pragma unroll
        for (int i=0;i<4;i++){
            int id = i*256+t; int kk = id&31; int r = id>>5;
            int row = rowBase + r;
            As[kk*36+r] = (row<NG) ? ao[(size_t)row*F + kb + kk] : 0.f;
        }
        #pragma unroll
        for (int i=0;i<16;i++){
            int id = i*256+t; int c = id&127; int kk = id>>7;
            Bs[kk*128+c] = Wo[(size_t)(kb+kk)*F + c];
        }
        __syncthreads();
        for (int kk=0;kk<32;kk++){
            float4 a = *(const float4*)&As[kk*36+r0];
            float4 bv = *(const float4*)&Bs[kk*128+c0];
            float av[4]={a.x,a.y,a.z,a.w}; float bb[4]={bv.x,bv.y,bv.z,bv.w};
            #pragma unroll
            for(int i=0;i<4;i++)
                #pragma unroll
                for(int j=0;j<4;j++) acc[i][j] += av[i]*bb[j];
        }
        __syncthreads();
    }
    float4 bo4 = *(const float4*)&bo[c0];
    float4 g4  = *(const float4*)&g[c0];
    float4 b4  = *(const float4*)&b[c0];
    #pragma unroll
    for (int i=0;i<4;i++){
        int row = rowBase + r0 + i;
        float v0=0.f,v1=0.f,v2=0.f,v3=0.f;
        if (row < NG){
            float4 zr = *(const float4*)&z[(size_t)row*F + c0];
            v0 = acc[i][0] + bo4.x + zr.x;
            v1 = acc[i][1] + bo4.y + zr.y;
            v2 = acc[i][2] + bo4.z + zr.z;
            v3 = acc[i][3] + bo4.w + zr.w;
        }
        float s = (v0+v1)+(v2+v3);
        #pragma unroll
        for (int off=1; off<32; off<<=1) s += __shfl_xor(s, off);
        float m = s * (1.f/128.f);
        float d0=v0-m, d1=v1-m, d2=v2-m, d3=v3-m;
        float vv = (d0*d0+d1*d1)+(d2*d2+d3*d3);
        #pragma unroll
        for (int off=1; off<32; off<<=1) vv += __shfl_xor(vv, off);
        float rs = rsqrtf(vv*(1.f/128.f) + 1e-5f);
        if (row < NG){
            float o0 = d0*rs*g4.x+b4.x, o1 = d1*rs*g4.y+b4.y;
            float o2 = d2*rs*g4.z+b4.z, o3 = d3*rs*g4.w+b4.w;
            *(float4*)&zd1[(size_t)row*F + c0] = make_float4(o0,o1,o2,o3);
            *(uint2*)&zd1b32[(size_t)row*(F/2) + c0/2] = make_uint2(pk2(o0,o1), pk2(o2,o3));
        }
    }
}

// ---------------- fused: zd2 = LN(zd1 + sum(part) + b2); gsi = zd2 @ Wg_bot + bg ----------------
__global__ __launch_bounds__(256) void k_ln_red_gsi(const float* __restrict__ A, const float* __restrict__ part,
                                                    const float* __restrict__ bias, const float* __restrict__ g,
                                                    const float* __restrict__ b, const float* __restrict__ Wb,
                                                    const float* __restrict__ bg, float* __restrict__ zd2,
                                                    float* __restrict__ gsi){
    __shared__ float Zs[4][128];
    __shared__ float Bs[32*128];
    int t = threadIdx.x; int lane = t&63;
    int rquad = t>>6;
    int row = blockIdx.x*4 + rquad;
    int i0 = row*F + 2*lane;
    float x0 = A[i0] + bias[2*lane], x1 = A[i0+1] + bias[2*lane+1];
    #pragma unroll
    for (int zz=0; zz<KSPLIT; ++zz){
        x0 += part[(size_t)zz*NG*F + i0];
        x1 += part[(size_t)zz*NG*F + i0 + 1];
    }
    float s = x0+x1;
    for (int off=1; off<64; off<<=1) s += __shfl_xor(s, off);
    float m = s * (1.f/128.f);
    float d0 = x0-m, d1 = x1-m;
    float vv = d0*d0 + d1*d1;
    for (int off=1; off<64; off<<=1) vv += __shfl_xor(vv, off);
    float rs = rsqrtf(vv*(1.f/128.f) + 1e-5f);
    float o0 = d0*rs*g[2*lane]   + b[2*lane];
    float o1 = d1*rs*g[2*lane+1] + b[2*lane+1];
    zd2[i0]   = o0;
    zd2[i0+1] = o1;
    Zs[rquad][2*lane]   = o0;
    Zs[rquad][2*lane+1] = o1;
    __syncthreads();
    int col = t & 127, rp = t >> 7;
    float a0=0.f, a1=0.f;
    for (int kb=0; kb<F; kb+=32){
        #pragma unroll
        for (int i=0;i<16;i++){
            int id = i*256+t; int c = id&127; int kk = id>>7;
            Bs[kk*128+c] = Wb[(size_t)(kb+kk)*F + c];
        }
        __syncthreads();
        for (int kk=0;kk<32;kk++){
            float w = Bs[kk*128+col];
            a0 += Zs[rp][kb+kk]   * w;
            a1 += Zs[rp+2][kb+kk] * w;
        }
        __syncthreads();
    }
    float bgc = bg[col];
    gsi[(size_t)(blockIdx.x*4 + rp)*F + col]     = a0 + bgc;
    gsi[(size_t)(blockIdx.x*4 + rp + 2)*F + col] = a1 + bgc;
}

// ---------------- attention: one block per (set, head) ----------------
__global__ __launch_bounds__(256) void k_attn(const float* __restrict__ q, const float* __restrict__ k,
                                              const float* __restrict__ v, float* __restrict__ o){
    __shared__ float Qs[1600], Ks[1600], Vs[1600], Sc[2500];
    int t = threadIdx.x;
    int s = blockIdx.x >> 2; int hh = blockIdx.x & 3;
    for (int idx=t; idx<1600; idx+=256){
        int i = idx>>5, d = idx&31;
        size_t gi = (size_t)(s*50+i)*F + hh*32 + d;
        Qs[idx]=q[gi]; Ks[idx]=k[gi]; Vs[idx]=v[gi];
    }
    __syncthreads();
    for (int idx=t; idx<2500; idx+=256){
        int qi = idx/50, ki = idx%50;
        float acc=0.f;
        #pragma unroll 8
        for (int d=0;d<32;d++) acc += Qs[qi*32+d]*Ks[ki*32+d];
        Sc[idx] = acc * 0.17677669529663687f;   // 1/sqrt(32)
    }
    __syncthreads();
    if (t < 50){
        float m=-1e30f;
        for (int j=0;j<50;j++) m = fmaxf(m, Sc[t*50+j]);
        float sum=0.f;
        for (int j=0;j<50;j++){ float e=__expf(Sc[t*50+j]-m); Sc[t*50+j]=e; sum+=e; }
        float inv = 1.f/sum;
        for (int j=0;j<50;j++) Sc[t*50+j] *= inv;
    }
    __syncthreads();
    for (int idx=t; idx<1600; idx+=256){
        int qi = idx>>5, d = idx&31;
        float acc=0.f;
        #pragma unroll 10
        for (int ki=0;ki<50;ki++) acc += Sc[qi*50+ki]*Vs[ki*32+d];
        o[(size_t)(s*50+qi)*F + hh*32 + d] = acc;
    }
}

// ---------------- MFMA gate: 64-row tiles, B from global bf16 Wgb (no LDS, no barriers) ----------------
// B-fragment Wgb[(nt*16+lr)*128 + kb] is byte-identical data to the old LDS path.
__global__ __launch_bounds__(256) void k_gate_mfma(const float* __restrict__ h,
                                                   const unsigned short* __restrict__ hb,
                                                   const unsigned short* __restrict__ Wgb,
                                                   const float* __restrict__ gsi, const float* __restrict__ zd2,
                                                   float* __restrict__ out){
    int t = threadIdx.x;
    int lane = t & 63, w = t >> 6;
    int lr = lane & 15, quad = lane >> 4;
    int mrow0 = blockIdx.x*64 + w*16;
    f32x4 acc[8];
    #pragma unroll
    for (int j=0;j<8;j++) acc[j] = (f32x4){0.f,0.f,0.f,0.f};
    #pragma unroll
    for (int ks=0; ks<4; ++ks){
        int kb = ks*32 + quad*8;
        int row = mrow0 + lr;
        if (row >= NN) row = NN-1;
        short8 a = *(const short8*)&hb[(size_t)row*F + kb];
        #pragma unroll
        for (int nt=0; nt<8; ++nt){
            short8 b = *(const short8*)&Wgb[(size_t)(nt*16 + lr)*128 + kb];
            acc[nt] = __builtin_amdgcn_mfma_f32_16x16x32_bf16(a, b, acc[nt], 0, 0, 0);
        }
    }
    // epilogue: C/D layout col=lane&15, row=quad*4+reg
    #pragma unroll
    for (int r=0; r<4; ++r){
        int row = mrow0 + quad*4 + r;
        if (row >= NN) continue;
        int g = row / 50;
        const float* gs = &gsi[(size_t)g*F];
        const float* zs = &zd2[(size_t)g*F];
        const float* hr = &h[(size_t)row*F];
        float* orow = &out[(size_t)row*F];
        #pragma unroll
        for (int nt=0; nt<8; ++nt){
            int col = nt*16 + lr;
            float L = acc[nt][r] + gs[col];
            float gate = 1.f/(1.f + __expf(-L));
            orow[col] = gate*zs[col] + (1.f-gate)*hr[col];
        }
    }
}

extern "C" void kernel_launch(void* const* d_in, const int* in_sizes, int n_in,
                              void* d_out, int out_size, void* d_ws, size_t ws_size,
                              hipStream_t stream) {
    const float* x      = (const float*)d_in[0];
    const int*   ei     = (const int*)d_in[1];
    const float* W_gcn  = (const float*)d_in[4];
    const float* b_gcn  = (const float*)d_in[5];
    const float* bn_g   = (const float*)d_in[6];
    const float* bn_b   = (const float*)d_in[7];
    const float* lnpre_g= (const float*)d_in[8];
    const float* lnpre_b= (const float*)d_in[9];
    const float* Wq     = (const float*)d_in[10];
    const float* bq     = (const float*)d_in[11];
    const float* Wk     = (const float*)d_in[12];
    const float* bk     = (const float*)d_in[13];
    const float* Wv     = (const float*)d_in[14];
    const float* bv     = (const float*)d_in[15];
    const float* Wo     = (const float*)d_in[16];
    const float* bo     = (const float*)d_in[17];
    const float* ln1_g  = (const float*)d_in[18];
    const float* ln1_b  = (const float*)d_in[19];
    const float* W1     = (const float*)d_in[20];
    const float* b1     = (const float*)d_in[21];
    const float* W2     = (const float*)d_in[22];
    const float* b2     = (const float*)d_in[23];
    const float* ln2_g  = (const float*)d_in[24];
    const float* ln2_b  = (const float*)d_in[25];
    const float* Wg     = (const float*)d_in[26];
    const float* bg     = (const float*)d_in[27];
    float* out = (float*)d_out;
    char* ws = (char*)d_ws;

    // workspace layout
    size_t o = 0;
    unsigned char* xws8 = (unsigned char*)(ws + o); o += (size_t)NN*F; // 12.8 MB (fp8)
    float* h     = (float*)(ws + o); o += (size_t)NN*F*4;            // 51.2 MB
    unsigned short* hb = (unsigned short*)(ws + o); o += (size_t)NN*F*2; // 25.6 MB (bf16)
    int*   cnt   = (int*)(ws + o);   o += (size_t)NN*4;
    int*   nstart= (int*)(ws + o);   o += (size_t)NN*4;
    int*   ebuf  = (int*)(ws + o);   o += (size_t)NB*BCAP*4;         // 9.6 MB
    int*   ebuf2 = (int*)(ws + o);   o += (size_t)NB*BCAP*4;         // 9.6 MB
    float* dinv  = (float*)(ws + o); o += (size_t)NN*4;
    int*   bcursor=(int*)(ws + o);   o += 1024*4;
    unsigned short* Wgb = (unsigned short*)(ws + o); o += 16384*2;   // 32 KB bf16 Wg_top^T
    float* z     = (float*)(ws + o); o += (size_t)NG*F*4;
    float* zn    = (float*)(ws + o); o += (size_t)NG*F*4;
    unsigned short* znb = (unsigned short*)(ws + o); o += (size_t)NG*F*2;
    float* qb    = (float*)(ws + o); o += (size_t)NG*F*4;
    float* kb2   = (float*)(ws + o); o += (size_t)NG*F*4;
    float* vb    = (float*)(ws + o); o += (size_t)NG*F*4;
    float* ao    = (float*)(ws + o); o += (size_t)NG*F*4;
    float* zd1   = (float*)(ws + o); o += (size_t)NG*F*4;
    unsigned short* zd1b = (unsigned short*)(ws + o); o += (size_t)NG*F*2;
    unsigned short* ffn1b = (unsigned short*)(ws + o); o += (size_t)NG*FFN_DIM*2; // 4.1 MB
    float* part  = (float*)(ws + o); o += (size_t)KSPLIT*NG*F*4;     // 8.2 MB
    float* zd2   = (float*)(ws + o); o += (size_t)NG*F*4;
    float* gsi   = (float*)(ws + o); o += (size_t)NG*F*4;

    // ---- GCN phase ----
    k_binit<<<1, 1024, 0, stream>>>(bcursor);
    k_wcvt<<<16, 256, 0, stream>>>(Wg, Wgb);
    k_scatter2<<<SC_BLOCKS, 1024, 0, stream>>>(ei, bcursor, ebuf);
    k_sort<<<NB, 256, 0, stream>>>(ebuf, bcursor, cnt, dinv, nstart, ebuf2);
    k_xws<<<(NN+127)/128, 256, 0, stream>>>(x, W_gcn, dinv, xws8);
    k_aggpool<<<NG, 256, 0, stream>>>(xws8, nstart, cnt, dinv, b_gcn, bn_g, bn_b, ebuf2,
                                      lnpre_g, lnpre_b, h, hb, z, zn, znb);

    // ---- set transformer (bf16 MFMA GEMMs, fp32 LN/attn) ----
    dim3 gqkv((NG+127)/128, 1, 3);
    k_qkv_mfma<<<gqkv, 256, 0, stream>>>(znb, Wq, Wk, Wv, bq, bk, bv, qb, kb2, vb);
    k_attn<<<NS*4, 256, 0, stream>>>(qb, kb2, vb, ao);
    k_wo_ln<<<(NG+31)/32, 256, 0, stream>>>(ao, Wo, bo, z, ln1_g, ln1_b, zd1, zd1b);
    dim3 gffn1((NG+127)/128, FFN_DIM/128, 1);
    k_mm_bf16<1,1,0><<<gffn1, 256, 0, stream>>>(zd1b, W1, b1, nullptr, ffn1b, NG, F, FFN_DIM);
    dim3 gffn2((NG+127)/128, 1, KSPLIT);
    k_mm_bf16<0,0,1><<<gffn2, 256, 0, stream>>>(ffn1b, W2, nullptr, part, nullptr, NG, FFN_DIM, F);
    k_ln_red_gsi<<<NG/4, 256, 0, stream>>>(zd1, part, b2, ln2_g, ln2_b,
                                           Wg + (size_t)F*F, bg, zd2, gsi);

    // ---- gated fusion -> output ----
    k_gate_mfma<<<(NN+63)/64, 256, 0, stream>>>(h, hb, Wgb, gsi, zd2, out);
}